// Round 15
// baseline (155.975 us; speedup 1.0000x reference)
//
#include <hip/hip_runtime.h>
#include <hip/hip_bf16.h>

// B=2, T=2048, D=1024, H=16, dh=64. f32 in/out, bf16 MFMA internally.
// R15: attn q32 with g-SPLIT PV: per-wave P buffer back to 16 rows (LDS
// 70.6->53.2KB => 3 blocks/CU, R14 was 2) while keeping K-frag reuse across
// both 16-row groups. V frags read twice (the cheaper half of the trade).
// GEMMs/prep/combine identical to R14.

typedef __attribute__((ext_vector_type(8))) short bf16x8;
typedef __attribute__((ext_vector_type(4))) float f32x4;

__device__ __forceinline__ ushort f2bf(float f) {
  unsigned u = __builtin_bit_cast(unsigned, f);
  unsigned r = (u + 0x7fffu + ((u >> 16) & 1u)) >> 16;   // RNE
  return (ushort)r;
}
__device__ __forceinline__ float bf2f(ushort u) {
  unsigned v = ((unsigned)u) << 16;
  return __builtin_bit_cast(float, v);
}
__device__ __forceinline__ unsigned cvtpk(float a, float b) {  // [lo=a, hi=b] bf16, RNE
  unsigned r;
  asm("v_cvt_pk_bf16_f32 %0, %1, %2" : "=v"(r) : "v"(a), "v"(b));
  return r;
}

__device__ __forceinline__ void gload16(const ushort* g, ushort* l) {
  auto gp = (const __attribute__((address_space(1))) void*)g;
  auto lp = (__attribute__((address_space(3))) void*)l;
  __builtin_amdgcn_global_load_lds(gp, lp, 16, 0, 0);
}

// chunks per 128-row q-block a (k = a+1 kv tiles); must match attn/combine
__device__ __forceinline__ int nch2_of(int a) {
  if (a >= 8) return (a + 2) >> 1;   // 2-tile chunks: ceil((a+1)/2)
  if (a >= 4) return 2;              // 4-tile chunks, k=5..8
  return 1;                          // k<=4, single chunk
}

// ---------------- prep: x cvt + w_qkv^T + w_proj^T in ONE launch ----------------
__global__ __launch_bounds__(256) void prep(const float* __restrict__ x,
                                            const float* __restrict__ wq,
                                            const float* __restrict__ wp,
                                            ushort* __restrict__ xb,
                                            ushort* __restrict__ wqT,
                                            ushort* __restrict__ wpT) {
  __shared__ float tile[32][33];
  const int bx = blockIdx.x;
  if (bx < 4096) {
    int i = (bx * 256 + threadIdx.x) * 4;     // 4096*256*4 = |x|
    float4 v = *(const float4*)(x + i);
    ushort4 o = { f2bf(v.x), f2bf(v.y), f2bf(v.z), f2bf(v.w) };
    *(ushort4*)(xb + i) = o;
    return;
  }
  const float* in;  ushort* out;  int C, b2;
  if (bx < 7168) { b2 = bx - 4096; in = wq; out = wqT; C = 3072; }
  else           { b2 = bx - 7168; in = wp; out = wpT; C = 1024; }
  const int R = 1024;
  int nbx = C / 32;
  int c0 = (b2 % nbx) * 32, r0 = (b2 / nbx) * 32;
  int tx = threadIdx.x & 31, ty = threadIdx.x >> 5;
  #pragma unroll
  for (int i = 0; i < 32; i += 8) tile[ty + i][tx] = in[(size_t)(r0 + ty + i) * C + c0 + tx];
  __syncthreads();
  #pragma unroll
  for (int i = 0; i < 32; i += 8) out[(size_t)(c0 + ty + i) * R + r0 + tx] = f2bf(tile[tx][ty + i]);
}

// ---------------- bf16 GEMM: C[M,N] = A[M,K] * BT[N,K]^T, XCD-chunked 1D grid --------
template <int EPI, int BN>
__global__ __launch_bounds__(256) void gemm_bf16(const ushort* __restrict__ A,
                                                 const ushort* __restrict__ BT,
                                                 ushort* __restrict__ qo, ushort* __restrict__ ko,
                                                 ushort* __restrict__ vo, float* __restrict__ outf,
                                                 int M, int N, int K) {
  constexpr int NB = BN / 32;
  constexpr int ABU = 128 * 32 + BN * 32;
  constexpr int SHU = (EPI == 0 && 2 * 128 * 72 > ABU) ? 2 * 128 * 72 : ABU;
  __shared__ ushort sh[SHU];
  ushort* Als = sh;
  ushort* Bls = sh + 128 * 32;
  const int tid = threadIdx.x;
  const int lane = tid & 63;
  const int w = tid >> 6;
  const int wr = w >> 1, wc = w & 1;
  const int fr = lane & 15, fq = lane >> 4;
  const int flat = blockIdx.x;
  const int cpx = (32 * (N / BN)) >> 3;
  const int swz = (flat & 7) * cpx + (flat >> 3);
  const int bm0 = (swz & 31) * 128;
  const int bn0 = (swz >> 5) * BN;
  const int srow = lane >> 2;
  const int scol = (lane & 3) * 8;

  f32x4 acc[4][NB];
  #pragma unroll
  for (int m = 0; m < 4; m++)
    #pragma unroll
    for (int n = 0; n < NB; n++) acc[m][n] = (f32x4){0.f, 0.f, 0.f, 0.f};

  for (int k0 = 0; k0 < K; k0 += 32) {
    __syncthreads();
    #pragma unroll
    for (int c = 0; c < 2; c++) {
      int chunk = w * 2 + c;
      int rr = chunk * 16 + srow;
      gload16(&A[(size_t)(bm0 + rr) * K + k0 + scol], &Als[chunk * 512]);
    }
    #pragma unroll
    for (int c = 0; c < BN / 64; c++) {
      int chunk = w * (BN / 64) + c;
      int rr = chunk * 16 + srow;
      gload16(&BT[(size_t)(bn0 + rr) * K + k0 + scol], &Bls[chunk * 512]);
    }
    __syncthreads();
    bf16x8 a[4], b[NB];
    #pragma unroll
    for (int m = 0; m < 4; m++) a[m] = *(bf16x8*)&Als[(wr * 64 + m * 16 + fr) * 32 + fq * 8];
    #pragma unroll
    for (int n = 0; n < NB; n++) b[n] = *(bf16x8*)&Bls[(wc * (BN / 2) + n * 16 + fr) * 32 + fq * 8];
    __builtin_amdgcn_s_setprio(1);
    #pragma unroll
    for (int m = 0; m < 4; m++)
      #pragma unroll
      for (int n = 0; n < NB; n++)
        acc[m][n] = __builtin_amdgcn_mfma_f32_16x16x32_bf16(a[m], b[n], acc[m][n], 0, 0, 0);
    __builtin_amdgcn_s_setprio(0);
  }

  if (EPI == 0) {
    __syncthreads();
    ushort* vst = sh;
    #pragma unroll
    for (int m = 0; m < 4; m++)
      #pragma unroll
      for (int n = 0; n < NB; n++)
        #pragma unroll
        for (int jj = 0; jj < 4; jj++) {
          int lt = wr * 64 + m * 16 + fq * 4 + jj;
          int dd = n * 16 + fr;
          vst[(wc * 128 + lt) * 72 + dd] = f2bf(acc[m][n][jj]);
        }
    __syncthreads();
    const int b_ = bm0 >> 11, t0loc = bm0 & 2047;
    const int which = bn0 >> 10;
    const int hbase = (bn0 & 1023) >> 6;
    if (which < 2) {
      ushort* dst = (which == 0) ? qo : ko;
      #pragma unroll
      for (int p = 0; p < 8; p++) {
        int idx = tid + p * 256;
        int hh = idx >> 10, lt = (idx >> 3) & 127, c8 = (idx & 7) * 8;
        uint4 v = *(uint4*)&vst[(hh * 128 + lt) * 72 + c8];
        size_t bh = (size_t)(b_ * 16 + hbase + hh);
        *(uint4*)&dst[(bh * 2048 + t0loc + lt) * 64 + c8] = v;
      }
    } else {
      #pragma unroll
      for (int p = 0; p < 8; p++) {
        int idx = tid + p * 256;
        int hh = idx >> 10, d = (idx >> 4) & 63, m = idx & 15;
        ushort vals[8];
        #pragma unroll
        for (int e = 0; e < 8; e++) vals[e] = vst[(hh * 128 + 16 * e + m) * 72 + d];
        size_t bh = (size_t)(b_ * 16 + hbase + hh);
        *(uint4*)&vo[(bh * 64 + d) * 2048 + t0loc + 8 * m] = *(uint4*)vals;
      }
    }
  } else {
    #pragma unroll
    for (int m = 0; m < 4; m++)
      #pragma unroll
      for (int n = 0; n < NB; n++)
        #pragma unroll
        for (int jj = 0; jj < 4; jj++) {
          int r = bm0 + wr * 64 + m * 16 + fq * 4 + jj;
          int c = bn0 + wc * (BN / 2) + n * 16 + fr;
          outf[(size_t)r * N + c] = acc[m][n][jj];
        }
  }
}

// ---------------- split-KV flash attention (causal), q32 waves, g-split PV ----------
// Block = 128 q-rows; wave w owns 32 q-rows as two 16-row groups (g=0,1).
// QK^T: K frag reads feed 2 MFMAs. PV: g-split through a 16-row per-wave P
// buffer (LDS 53.2KB -> 3 blocks/CU). grid 2048: bh=bx&31, i=bx>>5.
__global__ __launch_bounds__(256, 3) void attn_fwd(const ushort* __restrict__ qg,
                                                   const ushort* __restrict__ kg,
                                                   const ushort* __restrict__ vtg,
                                                   ushort* __restrict__ y,
                                                   ushort* __restrict__ pO,
                                                   float* __restrict__ pl) {
  __shared__ ushort Ks[128 * 72];      // [kv][d]
  __shared__ ushort Vt[64 * 136];      // [d][kv'] (kv permuted)
  __shared__ ushort Ps[4][16 * 136];   // per-wave P [q16][kv'128], reused g=0,1

  const int bh = blockIdx.x & 31;
  const int i = blockIdx.x >> 5;       // 0..63, a descending
  int acc = 0, a = 15, nch = 1;
  for (int q = 15; q >= 0; --q) {
    int nc = nch2_of(q);
    if (i < acc + nc) { a = q; nch = nc; break; }
    acc += nc;
  }
  const int ch = i - acc;
  const int k = a + 1;
  const int ct = (a >= 8) ? 2 : 4;
  const int t0 = ch * ct;
  const int t1 = (t0 + ct < k) ? t0 + ct : k;

  const int tid = threadIdx.x, lane = tid & 63, w = tid >> 6;
  const int fr = lane & 15, fq = lane >> 4;
  const size_t base = (size_t)bh * 2048 * 64;
  const int b_ = bh >> 4, h = bh & 15;
  const int qb0 = a * 128;
  ushort* P_ = Ps[w];

  const int sr = tid >> 3;          // 0..31
  const int sc = (tid & 7) * 8;
  const int vr = tid >> 4;          // 0..15
  const int vc = (tid & 15) * 8;
  const ushort* kg_l = kg + base + (size_t)sr * 64 + sc;
  const ushort* vg_l = vtg + base + (size_t)vr * 2048 + vc;

  bf16x8 qf[2][2];
  #pragma unroll
  for (int g = 0; g < 2; g++) {
    const ushort* qp = &qg[base + (size_t)(qb0 + w * 32 + g * 16 + fr) * 64];
    qf[g][0] = *(const bf16x8*)(qp + fq * 8);
    qf[g][1] = *(const bf16x8*)(qp + 32 + fq * 8);
  }

  f32x4 o[2][4];
  #pragma unroll
  for (int g = 0; g < 2; g++)
    #pragma unroll
    for (int n = 0; n < 4; n++) o[g][n] = (f32x4){0.f, 0.f, 0.f, 0.f};
  float l_[2][4] = {{0.f,0.f,0.f,0.f},{0.f,0.f,0.f,0.f}};

  uint4 k0r, k1r, k2r, k3r, v0r, v1r, v2r, v3r;  // named: cannot lower to scratch

#define LOADT(t)                                                   \
  do {                                                             \
    const ushort* kp = kg_l + (size_t)(t) * 8192;                  \
    k0r = *(const uint4*)(kp);         k1r = *(const uint4*)(kp + 2048); \
    k2r = *(const uint4*)(kp + 4096);  k3r = *(const uint4*)(kp + 6144); \
    const ushort* vp = vg_l + (size_t)(t) * 128;                   \
    v0r = *(const uint4*)(vp);              v1r = *(const uint4*)(vp + 16 * 2048); \
    v2r = *(const uint4*)(vp + 32 * 2048);  v3r = *(const uint4*)(vp + 48 * 2048); \
  } while (0)

  const float C_EXP2 = 0.18033688011112042f;  // 0.125 * log2(e)

  LOADT(t0);
  for (int t = t0; t < t1; ++t) {
    const int kv0 = t * 128;
    if (t > t0) __syncthreads();
    *(uint4*)&Ks[(size_t)sr * 72 + sc] = k0r;
    *(uint4*)&Ks[(size_t)(sr + 32) * 72 + sc] = k1r;
    *(uint4*)&Ks[(size_t)(sr + 64) * 72 + sc] = k2r;
    *(uint4*)&Ks[(size_t)(sr + 96) * 72 + sc] = k3r;
    *(uint4*)&Vt[(size_t)vr * 136 + vc] = v0r;
    *(uint4*)&Vt[(size_t)(vr + 16) * 136 + vc] = v1r;
    *(uint4*)&Vt[(size_t)(vr + 32) * 136 + vc] = v2r;
    *(uint4*)&Vt[(size_t)(vr + 48) * 136 + vc] = v3r;
    __syncthreads();

    if (t + 1 < t1) LOADT(t + 1);  // prefetch in flight across compute

    // S = Q K^T : [32 q] x [128 kv]; each K frag read feeds 2 MFMAs
    f32x4 s[2][8];
    #pragma unroll
    for (int g = 0; g < 2; g++)
      #pragma unroll
      for (int n = 0; n < 8; n++) s[g][n] = (f32x4){0.f, 0.f, 0.f, 0.f};
    __builtin_amdgcn_s_setprio(1);
    #pragma unroll
    for (int ks = 0; ks < 2; ks++)
      #pragma unroll
      for (int n = 0; n < 8; n++) {
        bf16x8 bk = *(bf16x8*)&Ks[(n * 16 + fr) * 72 + ks * 32 + fq * 8];
        s[0][n] = __builtin_amdgcn_mfma_f32_16x16x32_bf16(qf[0][ks], bk, s[0][n], 0, 0, 0);
        s[1][n] = __builtin_amdgcn_mfma_f32_16x16x32_bf16(qf[1][ks], bk, s[1][n], 0, 0, 0);
      }
    __builtin_amdgcn_s_setprio(0);

    // g-split: softmax(g) -> P_ (16 rows) -> PV(g); WAR/RAW ordered in-wave
    const bool lastT = (t == k - 1);
    #pragma unroll
    for (int g = 0; g < 2; g++) {
      #pragma unroll
      for (int j = 0; j < 4; j++) {
        const int qrow = qb0 + w * 32 + g * 16 + fq * 4 + j;
        float p[8];
        float rs = 0.f;
        #pragma unroll
        for (int n = 0; n < 8; n++) {
          float val = s[g][n][j] * C_EXP2;
          if (lastT && (kv0 + n * 16 + fr > qrow)) val = -1e30f;
          p[n] = __builtin_amdgcn_exp2f(val);
          rs += p[n];
        }
        l_[g][j] += rs;
        uint4 pk;
        pk.x = cvtpk(p[0], p[1]);
        pk.y = cvtpk(p[2], p[3]);
        pk.z = cvtpk(p[4], p[5]);
        pk.w = cvtpk(p[6], p[7]);
        *(uint4*)&P_[(fq * 4 + j) * 136 + 8 * fr] = pk;
      }
      __builtin_amdgcn_s_setprio(1);
      #pragma unroll
      for (int ks = 0; ks < 4; ks++) {
        bf16x8 pa = *(bf16x8*)&P_[fr * 136 + ks * 32 + fq * 8];
        #pragma unroll
        for (int n2 = 0; n2 < 4; n2++) {
          bf16x8 vb8 = *(bf16x8*)&Vt[(n2 * 16 + fr) * 136 + ks * 32 + fq * 8];
          o[g][n2] = __builtin_amdgcn_mfma_f32_16x16x32_bf16(pa, vb8, o[g][n2], 0, 0, 0);
        }
      }
      __builtin_amdgcn_s_setprio(0);
    }
  }
#undef LOADT

  #pragma unroll
  for (int g = 0; g < 2; g++)
    #pragma unroll
    for (int j = 0; j < 4; j++) {
      float rs = l_[g][j];
      rs += __shfl_xor(rs, 1);
      rs += __shfl_xor(rs, 2);
      rs += __shfl_xor(rs, 4);
      rs += __shfl_xor(rs, 8);
      l_[g][j] = rs;
    }

  if (nch == 1) {
    #pragma unroll
    for (int g = 0; g < 2; g++)
      #pragma unroll
      for (int n2 = 0; n2 < 4; n2++)
        #pragma unroll
        for (int j = 0; j < 4; j++) {
          int qrow = qb0 + w * 32 + g * 16 + fq * 4 + j;
          y[((size_t)(b_ * 2048 + qrow)) * 1024 + h * 64 + n2 * 16 + fr] =
              f2bf(o[g][n2][j] / l_[g][j]);
        }
  } else {
    const size_t ob = ((size_t)i * 32 + bh) * 128 * 64;
    #pragma unroll
    for (int g = 0; g < 2; g++)
      #pragma unroll
      for (int n2 = 0; n2 < 4; n2++)
        #pragma unroll
        for (int j = 0; j < 4; j++) {
          int qr = w * 32 + g * 16 + fq * 4 + j;
          pO[ob + (size_t)qr * 64 + n2 * 16 + fr] = f2bf(o[g][n2][j]);
        }
    if (fr == 0) {
      #pragma unroll
      for (int g = 0; g < 2; g++)
        #pragma unroll
        for (int j = 0; j < 4; j++)
          pl[((size_t)i * 32 + bh) * 128 + w * 32 + g * 16 + fq * 4 + j] = l_[g][j];
    }
  }
}

// ---------------- combine partials: y = (sum_c O_c) / (sum_c l_c) ----------------
__global__ __launch_bounds__(256) void attn_combine(const ushort* __restrict__ pO,
                                                    const float* __restrict__ pl,
                                                    ushort* __restrict__ y) {
  const int total = 32 * 2048 * 64;
  for (int flat = blockIdx.x * 256 + threadIdx.x; flat < total; flat += gridDim.x * 256) {
    int d = flat & 63;
    int t = (flat >> 6) & 2047;
    int bh = flat >> 17;
    int a = t >> 7;
    int nch = nch2_of(a);
    if (nch < 2) continue;
    int baseSlot = 0;
    for (int q = 15; q > a; --q) baseSlot += nch2_of(q);
    float os = 0.f, ls = 0.f;
    for (int c = 0; c < nch; ++c) {
      int slot = baseSlot + c;
      os += bf2f(pO[((size_t)slot * 32 + bh) * 128 * 64 + (size_t)(t & 127) * 64 + d]);
      ls += pl[((size_t)slot * 32 + bh) * 128 + (t & 127)];
    }
    int b_ = bh >> 4, h = bh & 15;
    y[((size_t)(b_ * 2048 + t)) * 1024 + h * 64 + d] = f2bf(os / ls);
  }
}

extern "C" void kernel_launch(void* const* d_in, const int* in_sizes, int n_in,
                              void* d_out, int out_size, void* d_ws, size_t ws_size,
                              hipStream_t stream) {
  const float* x = (const float*)d_in[0];
  const float* wqkv = (const float*)d_in[1];
  const float* wproj = (const float*)d_in[2];
  float* out = (float*)d_out;

  ushort* ws = (ushort*)d_ws;
  ushort* xb = ws;                               // 4096*1024
  ushort* wqkvT = xb + 4096 * 1024;              // 3072*1024  [N][K]
  ushort* wprojT = wqkvT + 3072 * 1024;          // 1024*1024  [N][K]
  ushort* qb = wprojT + 1024 * 1024;             // [bh][t][64]
  ushort* kb = qb + 32 * 2048 * 64;              // [bh][t][64]
  ushort* vtb = kb + 32 * 2048 * 64;             // [bh][64][t'] kv-permuted
  ushort* yb = vtb + 32 * 2048 * 64;             // [B,T,1024]
  ushort* pO = yb + 4096 * 1024;                 // [64 slots][32][128][64] bf16
  float*  pl = (float*)(pO + (size_t)64 * 32 * 128 * 64);  // [64][32][128] f32

  prep<<<8192, 256, 0, stream>>>(x, wqkv, wproj, xb, wqkvT, wprojT);
  gemm_bf16<0, 128><<<768, 256, 0, stream>>>(xb, wqkvT, qb, kb, vtb, nullptr, 4096, 3072, 1024);
  attn_fwd<<<2048, 256, 0, stream>>>(qb, kb, vtb, yb, pO, pl);
  attn_combine<<<2048, 256, 0, stream>>>(pO, pl, yb);
  gemm_bf16<1, 64><<<512, 256, 0, stream>>>(yb, wprojT, nullptr, nullptr, nullptr, out, 4096, 1024, 1024);
}

// Round 16
// 140.643 us; speedup vs baseline: 1.1090x; 1.1090x over previous
//
#include <hip/hip_runtime.h>
#include <hip/hip_bf16.h>

// B=2, T=2048, D=1024, H=16, dh=64. f32 in/out, bf16 MFMA internally.
// R16 = R15 with the spill fixed: attn launch_bounds (256,3)->(256,2).
// R15's (256,3) hard-capped VGPR below the ~116-reg live set -> 126MB scratch
// writes (the R3/R4 signature). (256,2) is R14's proven setting; kernel needs
// ~116 regs, <=128 => HW can still run 3 blocks/CU with LDS 53.2KB.

typedef __attribute__((ext_vector_type(8))) short bf16x8;
typedef __attribute__((ext_vector_type(4))) float f32x4;

__device__ __forceinline__ ushort f2bf(float f) {
  unsigned u = __builtin_bit_cast(unsigned, f);
  unsigned r = (u + 0x7fffu + ((u >> 16) & 1u)) >> 16;   // RNE
  return (ushort)r;
}
__device__ __forceinline__ float bf2f(ushort u) {
  unsigned v = ((unsigned)u) << 16;
  return __builtin_bit_cast(float, v);
}
__device__ __forceinline__ unsigned cvtpk(float a, float b) {  // [lo=a, hi=b] bf16, RNE
  unsigned r;
  asm("v_cvt_pk_bf16_f32 %0, %1, %2" : "=v"(r) : "v"(a), "v"(b));
  return r;
}

__device__ __forceinline__ void gload16(const ushort* g, ushort* l) {
  auto gp = (const __attribute__((address_space(1))) void*)g;
  auto lp = (__attribute__((address_space(3))) void*)l;
  __builtin_amdgcn_global_load_lds(gp, lp, 16, 0, 0);
}

// chunks per 128-row q-block a (k = a+1 kv tiles); must match attn/combine
__device__ __forceinline__ int nch2_of(int a) {
  if (a >= 8) return (a + 2) >> 1;   // 2-tile chunks: ceil((a+1)/2)
  if (a >= 4) return 2;              // 4-tile chunks, k=5..8
  return 1;                          // k<=4, single chunk
}

// ---------------- prep: x cvt + w_qkv^T + w_proj^T in ONE launch ----------------
__global__ __launch_bounds__(256) void prep(const float* __restrict__ x,
                                            const float* __restrict__ wq,
                                            const float* __restrict__ wp,
                                            ushort* __restrict__ xb,
                                            ushort* __restrict__ wqT,
                                            ushort* __restrict__ wpT) {
  __shared__ float tile[32][33];
  const int bx = blockIdx.x;
  if (bx < 4096) {
    int i = (bx * 256 + threadIdx.x) * 4;     // 4096*256*4 = |x|
    float4 v = *(const float4*)(x + i);
    ushort4 o = { f2bf(v.x), f2bf(v.y), f2bf(v.z), f2bf(v.w) };
    *(ushort4*)(xb + i) = o;
    return;
  }
  const float* in;  ushort* out;  int C, b2;
  if (bx < 7168) { b2 = bx - 4096; in = wq; out = wqT; C = 3072; }
  else           { b2 = bx - 7168; in = wp; out = wpT; C = 1024; }
  const int R = 1024;
  int nbx = C / 32;
  int c0 = (b2 % nbx) * 32, r0 = (b2 / nbx) * 32;
  int tx = threadIdx.x & 31, ty = threadIdx.x >> 5;
  #pragma unroll
  for (int i = 0; i < 32; i += 8) tile[ty + i][tx] = in[(size_t)(r0 + ty + i) * C + c0 + tx];
  __syncthreads();
  #pragma unroll
  for (int i = 0; i < 32; i += 8) out[(size_t)(c0 + ty + i) * R + r0 + tx] = f2bf(tile[tx][ty + i]);
}

// ---------------- bf16 GEMM: C[M,N] = A[M,K] * BT[N,K]^T, XCD-chunked 1D grid --------
template <int EPI, int BN>
__global__ __launch_bounds__(256) void gemm_bf16(const ushort* __restrict__ A,
                                                 const ushort* __restrict__ BT,
                                                 ushort* __restrict__ qo, ushort* __restrict__ ko,
                                                 ushort* __restrict__ vo, float* __restrict__ outf,
                                                 int M, int N, int K) {
  constexpr int NB = BN / 32;
  constexpr int ABU = 128 * 32 + BN * 32;
  constexpr int SHU = (EPI == 0 && 2 * 128 * 72 > ABU) ? 2 * 128 * 72 : ABU;
  __shared__ ushort sh[SHU];
  ushort* Als = sh;
  ushort* Bls = sh + 128 * 32;
  const int tid = threadIdx.x;
  const int lane = tid & 63;
  const int w = tid >> 6;
  const int wr = w >> 1, wc = w & 1;
  const int fr = lane & 15, fq = lane >> 4;
  const int flat = blockIdx.x;
  const int cpx = (32 * (N / BN)) >> 3;
  const int swz = (flat & 7) * cpx + (flat >> 3);
  const int bm0 = (swz & 31) * 128;
  const int bn0 = (swz >> 5) * BN;
  const int srow = lane >> 2;
  const int scol = (lane & 3) * 8;

  f32x4 acc[4][NB];
  #pragma unroll
  for (int m = 0; m < 4; m++)
    #pragma unroll
    for (int n = 0; n < NB; n++) acc[m][n] = (f32x4){0.f, 0.f, 0.f, 0.f};

  for (int k0 = 0; k0 < K; k0 += 32) {
    __syncthreads();
    #pragma unroll
    for (int c = 0; c < 2; c++) {
      int chunk = w * 2 + c;
      int rr = chunk * 16 + srow;
      gload16(&A[(size_t)(bm0 + rr) * K + k0 + scol], &Als[chunk * 512]);
    }
    #pragma unroll
    for (int c = 0; c < BN / 64; c++) {
      int chunk = w * (BN / 64) + c;
      int rr = chunk * 16 + srow;
      gload16(&BT[(size_t)(bn0 + rr) * K + k0 + scol], &Bls[chunk * 512]);
    }
    __syncthreads();
    bf16x8 a[4], b[NB];
    #pragma unroll
    for (int m = 0; m < 4; m++) a[m] = *(bf16x8*)&Als[(wr * 64 + m * 16 + fr) * 32 + fq * 8];
    #pragma unroll
    for (int n = 0; n < NB; n++) b[n] = *(bf16x8*)&Bls[(wc * (BN / 2) + n * 16 + fr) * 32 + fq * 8];
    __builtin_amdgcn_s_setprio(1);
    #pragma unroll
    for (int m = 0; m < 4; m++)
      #pragma unroll
      for (int n = 0; n < NB; n++)
        acc[m][n] = __builtin_amdgcn_mfma_f32_16x16x32_bf16(a[m], b[n], acc[m][n], 0, 0, 0);
    __builtin_amdgcn_s_setprio(0);
  }

  if (EPI == 0) {
    __syncthreads();
    ushort* vst = sh;
    #pragma unroll
    for (int m = 0; m < 4; m++)
      #pragma unroll
      for (int n = 0; n < NB; n++)
        #pragma unroll
        for (int jj = 0; jj < 4; jj++) {
          int lt = wr * 64 + m * 16 + fq * 4 + jj;
          int dd = n * 16 + fr;
          vst[(wc * 128 + lt) * 72 + dd] = f2bf(acc[m][n][jj]);
        }
    __syncthreads();
    const int b_ = bm0 >> 11, t0loc = bm0 & 2047;
    const int which = bn0 >> 10;
    const int hbase = (bn0 & 1023) >> 6;
    if (which < 2) {
      ushort* dst = (which == 0) ? qo : ko;
      #pragma unroll
      for (int p = 0; p < 8; p++) {
        int idx = tid + p * 256;
        int hh = idx >> 10, lt = (idx >> 3) & 127, c8 = (idx & 7) * 8;
        uint4 v = *(uint4*)&vst[(hh * 128 + lt) * 72 + c8];
        size_t bh = (size_t)(b_ * 16 + hbase + hh);
        *(uint4*)&dst[(bh * 2048 + t0loc + lt) * 64 + c8] = v;
      }
    } else {
      #pragma unroll
      for (int p = 0; p < 8; p++) {
        int idx = tid + p * 256;
        int hh = idx >> 10, d = (idx >> 4) & 63, m = idx & 15;
        ushort vals[8];
        #pragma unroll
        for (int e = 0; e < 8; e++) vals[e] = vst[(hh * 128 + 16 * e + m) * 72 + d];
        size_t bh = (size_t)(b_ * 16 + hbase + hh);
        *(uint4*)&vo[(bh * 64 + d) * 2048 + t0loc + 8 * m] = *(uint4*)vals;
      }
    }
  } else {
    #pragma unroll
    for (int m = 0; m < 4; m++)
      #pragma unroll
      for (int n = 0; n < NB; n++)
        #pragma unroll
        for (int jj = 0; jj < 4; jj++) {
          int r = bm0 + wr * 64 + m * 16 + fq * 4 + jj;
          int c = bn0 + wc * (BN / 2) + n * 16 + fr;
          outf[(size_t)r * N + c] = acc[m][n][jj];
        }
  }
}

// ---------------- split-KV flash attention (causal), q32 waves, g-split PV ----------
// Block = 128 q-rows; wave w owns 32 q-rows as two 16-row groups (g=0,1).
// QK^T: K frag reads feed 2 MFMAs. PV: g-split through a 16-row per-wave P
// buffer (LDS 53.2KB). launch_bounds(256,2): no forced VGPR cap (R15's (256,3)
// spilled); at ~116 VGPR the HW can still fit 3 blocks/CU.
__global__ __launch_bounds__(256, 2) void attn_fwd(const ushort* __restrict__ qg,
                                                   const ushort* __restrict__ kg,
                                                   const ushort* __restrict__ vtg,
                                                   ushort* __restrict__ y,
                                                   ushort* __restrict__ pO,
                                                   float* __restrict__ pl) {
  __shared__ ushort Ks[128 * 72];      // [kv][d]
  __shared__ ushort Vt[64 * 136];      // [d][kv'] (kv permuted)
  __shared__ ushort Ps[4][16 * 136];   // per-wave P [q16][kv'128], reused g=0,1

  const int bh = blockIdx.x & 31;
  const int i = blockIdx.x >> 5;       // 0..63, a descending
  int acc = 0, a = 15, nch = 1;
  for (int q = 15; q >= 0; --q) {
    int nc = nch2_of(q);
    if (i < acc + nc) { a = q; nch = nc; break; }
    acc += nc;
  }
  const int ch = i - acc;
  const int k = a + 1;
  const int ct = (a >= 8) ? 2 : 4;
  const int t0 = ch * ct;
  const int t1 = (t0 + ct < k) ? t0 + ct : k;

  const int tid = threadIdx.x, lane = tid & 63, w = tid >> 6;
  const int fr = lane & 15, fq = lane >> 4;
  const size_t base = (size_t)bh * 2048 * 64;
  const int b_ = bh >> 4, h = bh & 15;
  const int qb0 = a * 128;
  ushort* P_ = Ps[w];

  const int sr = tid >> 3;          // 0..31
  const int sc = (tid & 7) * 8;
  const int vr = tid >> 4;          // 0..15
  const int vc = (tid & 15) * 8;
  const ushort* kg_l = kg + base + (size_t)sr * 64 + sc;
  const ushort* vg_l = vtg + base + (size_t)vr * 2048 + vc;

  bf16x8 qf[2][2];
  #pragma unroll
  for (int g = 0; g < 2; g++) {
    const ushort* qp = &qg[base + (size_t)(qb0 + w * 32 + g * 16 + fr) * 64];
    qf[g][0] = *(const bf16x8*)(qp + fq * 8);
    qf[g][1] = *(const bf16x8*)(qp + 32 + fq * 8);
  }

  f32x4 o[2][4];
  #pragma unroll
  for (int g = 0; g < 2; g++)
    #pragma unroll
    for (int n = 0; n < 4; n++) o[g][n] = (f32x4){0.f, 0.f, 0.f, 0.f};
  float l_[2][4] = {{0.f,0.f,0.f,0.f},{0.f,0.f,0.f,0.f}};

  uint4 k0r, k1r, k2r, k3r, v0r, v1r, v2r, v3r;  // named: cannot lower to scratch

#define LOADT(t)                                                   \
  do {                                                             \
    const ushort* kp = kg_l + (size_t)(t) * 8192;                  \
    k0r = *(const uint4*)(kp);         k1r = *(const uint4*)(kp + 2048); \
    k2r = *(const uint4*)(kp + 4096);  k3r = *(const uint4*)(kp + 6144); \
    const ushort* vp = vg_l + (size_t)(t) * 128;                   \
    v0r = *(const uint4*)(vp);              v1r = *(const uint4*)(vp + 16 * 2048); \
    v2r = *(const uint4*)(vp + 32 * 2048);  v3r = *(const uint4*)(vp + 48 * 2048); \
  } while (0)

  const float C_EXP2 = 0.18033688011112042f;  // 0.125 * log2(e)

  LOADT(t0);
  for (int t = t0; t < t1; ++t) {
    const int kv0 = t * 128;
    if (t > t0) __syncthreads();
    *(uint4*)&Ks[(size_t)sr * 72 + sc] = k0r;
    *(uint4*)&Ks[(size_t)(sr + 32) * 72 + sc] = k1r;
    *(uint4*)&Ks[(size_t)(sr + 64) * 72 + sc] = k2r;
    *(uint4*)&Ks[(size_t)(sr + 96) * 72 + sc] = k3r;
    *(uint4*)&Vt[(size_t)vr * 136 + vc] = v0r;
    *(uint4*)&Vt[(size_t)(vr + 16) * 136 + vc] = v1r;
    *(uint4*)&Vt[(size_t)(vr + 32) * 136 + vc] = v2r;
    *(uint4*)&Vt[(size_t)(vr + 48) * 136 + vc] = v3r;
    __syncthreads();

    if (t + 1 < t1) LOADT(t + 1);  // prefetch in flight across compute

    // S = Q K^T : [32 q] x [128 kv]; each K frag read feeds 2 MFMAs
    f32x4 s[2][8];
    #pragma unroll
    for (int g = 0; g < 2; g++)
      #pragma unroll
      for (int n = 0; n < 8; n++) s[g][n] = (f32x4){0.f, 0.f, 0.f, 0.f};
    __builtin_amdgcn_s_setprio(1);
    #pragma unroll
    for (int ks = 0; ks < 2; ks++)
      #pragma unroll
      for (int n = 0; n < 8; n++) {
        bf16x8 bk = *(bf16x8*)&Ks[(n * 16 + fr) * 72 + ks * 32 + fq * 8];
        s[0][n] = __builtin_amdgcn_mfma_f32_16x16x32_bf16(qf[0][ks], bk, s[0][n], 0, 0, 0);
        s[1][n] = __builtin_amdgcn_mfma_f32_16x16x32_bf16(qf[1][ks], bk, s[1][n], 0, 0, 0);
      }
    __builtin_amdgcn_s_setprio(0);

    // g-split: softmax(g) -> P_ (16 rows) -> PV(g); WAR/RAW ordered in-wave
    const bool lastT = (t == k - 1);
    #pragma unroll
    for (int g = 0; g < 2; g++) {
      #pragma unroll
      for (int j = 0; j < 4; j++) {
        const int qrow = qb0 + w * 32 + g * 16 + fq * 4 + j;
        float p[8];
        float rs = 0.f;
        #pragma unroll
        for (int n = 0; n < 8; n++) {
          float val = s[g][n][j] * C_EXP2;
          if (lastT && (kv0 + n * 16 + fr > qrow)) val = -1e30f;
          p[n] = __builtin_amdgcn_exp2f(val);
          rs += p[n];
        }
        l_[g][j] += rs;
        uint4 pk;
        pk.x = cvtpk(p[0], p[1]);
        pk.y = cvtpk(p[2], p[3]);
        pk.z = cvtpk(p[4], p[5]);
        pk.w = cvtpk(p[6], p[7]);
        *(uint4*)&P_[(fq * 4 + j) * 136 + 8 * fr] = pk;
      }
      __builtin_amdgcn_s_setprio(1);
      #pragma unroll
      for (int ks = 0; ks < 4; ks++) {
        bf16x8 pa = *(bf16x8*)&P_[fr * 136 + ks * 32 + fq * 8];
        #pragma unroll
        for (int n2 = 0; n2 < 4; n2++) {
          bf16x8 vb8 = *(bf16x8*)&Vt[(n2 * 16 + fr) * 136 + ks * 32 + fq * 8];
          o[g][n2] = __builtin_amdgcn_mfma_f32_16x16x32_bf16(pa, vb8, o[g][n2], 0, 0, 0);
        }
      }
      __builtin_amdgcn_s_setprio(0);
    }
  }
#undef LOADT

  #pragma unroll
  for (int g = 0; g < 2; g++)
    #pragma unroll
    for (int j = 0; j < 4; j++) {
      float rs = l_[g][j];
      rs += __shfl_xor(rs, 1);
      rs += __shfl_xor(rs, 2);
      rs += __shfl_xor(rs, 4);
      rs += __shfl_xor(rs, 8);
      l_[g][j] = rs;
    }

  if (nch == 1) {
    #pragma unroll
    for (int g = 0; g < 2; g++)
      #pragma unroll
      for (int n2 = 0; n2 < 4; n2++)
        #pragma unroll
        for (int j = 0; j < 4; j++) {
          int qrow = qb0 + w * 32 + g * 16 + fq * 4 + j;
          y[((size_t)(b_ * 2048 + qrow)) * 1024 + h * 64 + n2 * 16 + fr] =
              f2bf(o[g][n2][j] / l_[g][j]);
        }
  } else {
    const size_t ob = ((size_t)i * 32 + bh) * 128 * 64;
    #pragma unroll
    for (int g = 0; g < 2; g++)
      #pragma unroll
      for (int n2 = 0; n2 < 4; n2++)
        #pragma unroll
        for (int j = 0; j < 4; j++) {
          int qr = w * 32 + g * 16 + fq * 4 + j;
          pO[ob + (size_t)qr * 64 + n2 * 16 + fr] = f2bf(o[g][n2][j]);
        }
    if (fr == 0) {
      #pragma unroll
      for (int g = 0; g < 2; g++)
        #pragma unroll
        for (int j = 0; j < 4; j++)
          pl[((size_t)i * 32 + bh) * 128 + w * 32 + g * 16 + fq * 4 + j] = l_[g][j];
    }
  }
}

// ---------------- combine partials: y = (sum_c O_c) / (sum_c l_c) ----------------
__global__ __launch_bounds__(256) void attn_combine(const ushort* __restrict__ pO,
                                                    const float* __restrict__ pl,
                                                    ushort* __restrict__ y) {
  const int total = 32 * 2048 * 64;
  for (int flat = blockIdx.x * 256 + threadIdx.x; flat < total; flat += gridDim.x * 256) {
    int d = flat & 63;
    int t = (flat >> 6) & 2047;
    int bh = flat >> 17;
    int a = t >> 7;
    int nch = nch2_of(a);
    if (nch < 2) continue;
    int baseSlot = 0;
    for (int q = 15; q > a; --q) baseSlot += nch2_of(q);
    float os = 0.f, ls = 0.f;
    for (int c = 0; c < nch; ++c) {
      int slot = baseSlot + c;
      os += bf2f(pO[((size_t)slot * 32 + bh) * 128 * 64 + (size_t)(t & 127) * 64 + d]);
      ls += pl[((size_t)slot * 32 + bh) * 128 + (t & 127)];
    }
    int b_ = bh >> 4, h = bh & 15;
    y[((size_t)(b_ * 2048 + t)) * 1024 + h * 64 + d] = f2bf(os / ls);
  }
}

extern "C" void kernel_launch(void* const* d_in, const int* in_sizes, int n_in,
                              void* d_out, int out_size, void* d_ws, size_t ws_size,
                              hipStream_t stream) {
  const float* x = (const float*)d_in[0];
  const float* wqkv = (const float*)d_in[1];
  const float* wproj = (const float*)d_in[2];
  float* out = (float*)d_out;

  ushort* ws = (ushort*)d_ws;
  ushort* xb = ws;                               // 4096*1024
  ushort* wqkvT = xb + 4096 * 1024;              // 3072*1024  [N][K]
  ushort* wprojT = wqkvT + 3072 * 1024;          // 1024*1024  [N][K]
  ushort* qb = wprojT + 1024 * 1024;             // [bh][t][64]
  ushort* kb = qb + 32 * 2048 * 64;              // [bh][t][64]
  ushort* vtb = kb + 32 * 2048 * 64;             // [bh][64][t'] kv-permuted
  ushort* yb = vtb + 32 * 2048 * 64;             // [B,T,1024]
  ushort* pO = yb + 4096 * 1024;                 // [64 slots][32][128][64] bf16
  float*  pl = (float*)(pO + (size_t)64 * 32 * 128 * 64);  // [64][32][128] f32

  prep<<<8192, 256, 0, stream>>>(x, wqkv, wproj, xb, wqkvT, wprojT);
  gemm_bf16<0, 128><<<768, 256, 0, stream>>>(xb, wqkvT, qb, kb, vtb, nullptr, 4096, 3072, 1024);
  attn_fwd<<<2048, 256, 0, stream>>>(qb, kb, vtb, yb, pO, pl);
  attn_combine<<<2048, 256, 0, stream>>>(pO, pl, yb);
  gemm_bf16<1, 64><<<512, 256, 0, stream>>>(yb, wprojT, nullptr, nullptr, nullptr, out, 4096, 1024, 1024);
}

// Round 17
// 117.641 us; speedup vs baseline: 1.3259x; 1.1955x over previous
//
#include <hip/hip_runtime.h>
#include <hip/hip_bf16.h>

// B=2, T=2048, D=1024, H=16, dh=64. f32 in/out, bf16 MFMA internally.
// R17: attn reverted to R14-exact (49us best; R15/R16 g-split closed as a loss).
// combine rewritten vectorized (uint4 pO loads, uint4 y stores, a>=4 rows only,
// closed-form baseSlot). prep tcvt writes vectorized (uint4).

typedef __attribute__((ext_vector_type(8))) short bf16x8;
typedef __attribute__((ext_vector_type(4))) float f32x4;

__device__ __forceinline__ ushort f2bf(float f) {
  unsigned u = __builtin_bit_cast(unsigned, f);
  unsigned r = (u + 0x7fffu + ((u >> 16) & 1u)) >> 16;   // RNE
  return (ushort)r;
}
__device__ __forceinline__ float bf2f(ushort u) {
  unsigned v = ((unsigned)u) << 16;
  return __builtin_bit_cast(float, v);
}
__device__ __forceinline__ unsigned cvtpk(float a, float b) {  // [lo=a, hi=b] bf16, RNE
  unsigned r;
  asm("v_cvt_pk_bf16_f32 %0, %1, %2" : "=v"(r) : "v"(a), "v"(b));
  return r;
}

__device__ __forceinline__ void gload16(const ushort* g, ushort* l) {
  auto gp = (const __attribute__((address_space(1))) void*)g;
  auto lp = (__attribute__((address_space(3))) void*)l;
  __builtin_amdgcn_global_load_lds(gp, lp, 16, 0, 0);
}

// chunks per 128-row q-block a (k = a+1 kv tiles); must match attn/combine
__device__ __forceinline__ int nch2_of(int a) {
  if (a >= 8) return (a + 2) >> 1;   // 2-tile chunks
  if (a >= 4) return 2;              // 4-tile chunks
  return 1;
}

// ---------------- prep: x cvt + w_qkv^T + w_proj^T in ONE launch ----------------
__global__ __launch_bounds__(256) void prep(const float* __restrict__ x,
                                            const float* __restrict__ wq,
                                            const float* __restrict__ wp,
                                            ushort* __restrict__ xb,
                                            ushort* __restrict__ wqT,
                                            ushort* __restrict__ wpT) {
  __shared__ float tile[32][33];
  const int bx = blockIdx.x;
  if (bx < 4096) {
    int i = (bx * 256 + threadIdx.x) * 4;     // full |x| coverage
    float4 v = *(const float4*)(x + i);
    ushort4 o = { f2bf(v.x), f2bf(v.y), f2bf(v.z), f2bf(v.w) };
    *(ushort4*)(xb + i) = o;
    return;
  }
  const float* in;  ushort* out;  int C, b2;
  if (bx < 7168) { b2 = bx - 4096; in = wq; out = wqT; C = 3072; }
  else           { b2 = bx - 7168; in = wp; out = wpT; C = 1024; }
  const int R = 1024;
  int nbx = C / 32;
  int c0 = (b2 % nbx) * 32, r0 = (b2 / nbx) * 32;
  int tx = threadIdx.x & 31, ty = threadIdx.x >> 5;
  #pragma unroll
  for (int i = 0; i < 32; i += 8) tile[ty + i][tx] = in[(size_t)(r0 + ty + i) * C + c0 + tx];
  __syncthreads();
  if (threadIdx.x < 128) {                       // vectorized transpose-writeback
    int cr = threadIdx.x >> 2, m = threadIdx.x & 3;
    ushort vals[8];
    #pragma unroll
    for (int e = 0; e < 8; e++) vals[e] = f2bf(tile[8 * m + e][cr]);
    *(uint4*)&out[(size_t)(c0 + cr) * R + r0 + 8 * m] = *(uint4*)vals;
  }
}

// ---------------- bf16 GEMM: C[M,N] = A[M,K] * BT[N,K]^T, XCD-chunked 1D grid --------
template <int EPI, int BN>
__global__ __launch_bounds__(256) void gemm_bf16(const ushort* __restrict__ A,
                                                 const ushort* __restrict__ BT,
                                                 ushort* __restrict__ qo, ushort* __restrict__ ko,
                                                 ushort* __restrict__ vo, float* __restrict__ outf,
                                                 int M, int N, int K) {
  constexpr int NB = BN / 32;
  constexpr int ABU = 128 * 32 + BN * 32;
  constexpr int SHU = (EPI == 0 && 2 * 128 * 72 > ABU) ? 2 * 128 * 72 : ABU;
  __shared__ ushort sh[SHU];
  ushort* Als = sh;
  ushort* Bls = sh + 128 * 32;
  const int tid = threadIdx.x;
  const int lane = tid & 63;
  const int w = tid >> 6;
  const int wr = w >> 1, wc = w & 1;
  const int fr = lane & 15, fq = lane >> 4;
  const int flat = blockIdx.x;
  const int cpx = (32 * (N / BN)) >> 3;
  const int swz = (flat & 7) * cpx + (flat >> 3);
  const int bm0 = (swz & 31) * 128;
  const int bn0 = (swz >> 5) * BN;
  const int srow = lane >> 2;
  const int scol = (lane & 3) * 8;

  f32x4 acc[4][NB];
  #pragma unroll
  for (int m = 0; m < 4; m++)
    #pragma unroll
    for (int n = 0; n < NB; n++) acc[m][n] = (f32x4){0.f, 0.f, 0.f, 0.f};

  for (int k0 = 0; k0 < K; k0 += 32) {
    __syncthreads();
    #pragma unroll
    for (int c = 0; c < 2; c++) {
      int chunk = w * 2 + c;
      int rr = chunk * 16 + srow;
      gload16(&A[(size_t)(bm0 + rr) * K + k0 + scol], &Als[chunk * 512]);
    }
    #pragma unroll
    for (int c = 0; c < BN / 64; c++) {
      int chunk = w * (BN / 64) + c;
      int rr = chunk * 16 + srow;
      gload16(&BT[(size_t)(bn0 + rr) * K + k0 + scol], &Bls[chunk * 512]);
    }
    __syncthreads();
    bf16x8 a[4], b[NB];
    #pragma unroll
    for (int m = 0; m < 4; m++) a[m] = *(bf16x8*)&Als[(wr * 64 + m * 16 + fr) * 32 + fq * 8];
    #pragma unroll
    for (int n = 0; n < NB; n++) b[n] = *(bf16x8*)&Bls[(wc * (BN / 2) + n * 16 + fr) * 32 + fq * 8];
    __builtin_amdgcn_s_setprio(1);
    #pragma unroll
    for (int m = 0; m < 4; m++)
      #pragma unroll
      for (int n = 0; n < NB; n++)
        acc[m][n] = __builtin_amdgcn_mfma_f32_16x16x32_bf16(a[m], b[n], acc[m][n], 0, 0, 0);
    __builtin_amdgcn_s_setprio(0);
  }

  if (EPI == 0) {
    __syncthreads();
    ushort* vst = sh;
    #pragma unroll
    for (int m = 0; m < 4; m++)
      #pragma unroll
      for (int n = 0; n < NB; n++)
        #pragma unroll
        for (int jj = 0; jj < 4; jj++) {
          int lt = wr * 64 + m * 16 + fq * 4 + jj;
          int dd = n * 16 + fr;
          vst[(wc * 128 + lt) * 72 + dd] = f2bf(acc[m][n][jj]);
        }
    __syncthreads();
    const int b_ = bm0 >> 11, t0loc = bm0 & 2047;
    const int which = bn0 >> 10;
    const int hbase = (bn0 & 1023) >> 6;
    if (which < 2) {
      ushort* dst = (which == 0) ? qo : ko;
      #pragma unroll
      for (int p = 0; p < 8; p++) {
        int idx = tid + p * 256;
        int hh = idx >> 10, lt = (idx >> 3) & 127, c8 = (idx & 7) * 8;
        uint4 v = *(uint4*)&vst[(hh * 128 + lt) * 72 + c8];
        size_t bh = (size_t)(b_ * 16 + hbase + hh);
        *(uint4*)&dst[(bh * 2048 + t0loc + lt) * 64 + c8] = v;
      }
    } else {
      #pragma unroll
      for (int p = 0; p < 8; p++) {
        int idx = tid + p * 256;
        int hh = idx >> 10, d = (idx >> 4) & 63, m = idx & 15;
        ushort vals[8];
        #pragma unroll
        for (int e = 0; e < 8; e++) vals[e] = vst[(hh * 128 + 16 * e + m) * 72 + d];
        size_t bh = (size_t)(b_ * 16 + hbase + hh);
        *(uint4*)&vo[(bh * 64 + d) * 2048 + t0loc + 8 * m] = *(uint4*)vals;
      }
    }
  } else {
    #pragma unroll
    for (int m = 0; m < 4; m++)
      #pragma unroll
      for (int n = 0; n < NB; n++)
        #pragma unroll
        for (int jj = 0; jj < 4; jj++) {
          int r = bm0 + wr * 64 + m * 16 + fq * 4 + jj;
          int c = bn0 + wc * (BN / 2) + n * 16 + fr;
          outf[(size_t)r * N + c] = acc[m][n][jj];
        }
  }
}

// ---------------- split-KV flash attention (causal), q32 waves — R14-exact ----------
__global__ __launch_bounds__(256, 2) void attn_fwd(const ushort* __restrict__ qg,
                                                   const ushort* __restrict__ kg,
                                                   const ushort* __restrict__ vtg,
                                                   ushort* __restrict__ y,
                                                   ushort* __restrict__ pO,
                                                   float* __restrict__ pl) {
  __shared__ ushort Ks[128 * 72];      // [kv][d]
  __shared__ ushort Vt[64 * 136];      // [d][kv'] (kv permuted)
  __shared__ ushort Ps[4][32 * 136];   // per-wave P [q32][kv'128]

  const int bh = blockIdx.x & 31;
  const int i = blockIdx.x >> 5;       // 0..63, a descending
  int acc = 0, a = 15, nch = 1;
  for (int q = 15; q >= 0; --q) {
    int nc = nch2_of(q);
    if (i < acc + nc) { a = q; nch = nc; break; }
    acc += nc;
  }
  const int ch = i - acc;
  const int k = a + 1;
  const int ct = (a >= 8) ? 2 : 4;
  const int t0 = ch * ct;
  const int t1 = (t0 + ct < k) ? t0 + ct : k;

  const int tid = threadIdx.x, lane = tid & 63, w = tid >> 6;
  const int fr = lane & 15, fq = lane >> 4;
  const size_t base = (size_t)bh * 2048 * 64;
  const int b_ = bh >> 4, h = bh & 15;
  const int qb0 = a * 128;
  ushort* P_ = Ps[w];

  const int sr = tid >> 3;          // 0..31
  const int sc = (tid & 7) * 8;
  const int vr = tid >> 4;          // 0..15
  const int vc = (tid & 15) * 8;
  const ushort* kg_l = kg + base + (size_t)sr * 64 + sc;
  const ushort* vg_l = vtg + base + (size_t)vr * 2048 + vc;

  bf16x8 qf[2][2];
  #pragma unroll
  for (int g = 0; g < 2; g++) {
    const ushort* qp = &qg[base + (size_t)(qb0 + w * 32 + g * 16 + fr) * 64];
    qf[g][0] = *(const bf16x8*)(qp + fq * 8);
    qf[g][1] = *(const bf16x8*)(qp + 32 + fq * 8);
  }

  f32x4 o[2][4];
  #pragma unroll
  for (int g = 0; g < 2; g++)
    #pragma unroll
    for (int n = 0; n < 4; n++) o[g][n] = (f32x4){0.f, 0.f, 0.f, 0.f};
  float l_[2][4] = {{0.f,0.f,0.f,0.f},{0.f,0.f,0.f,0.f}};

  uint4 k0r, k1r, k2r, k3r, v0r, v1r, v2r, v3r;  // named: cannot lower to scratch

#define LOADT(t)                                                   \
  do {                                                             \
    const ushort* kp = kg_l + (size_t)(t) * 8192;                  \
    k0r = *(const uint4*)(kp);         k1r = *(const uint4*)(kp + 2048); \
    k2r = *(const uint4*)(kp + 4096);  k3r = *(const uint4*)(kp + 6144); \
    const ushort* vp = vg_l + (size_t)(t) * 128;                   \
    v0r = *(const uint4*)(vp);              v1r = *(const uint4*)(vp + 16 * 2048); \
    v2r = *(const uint4*)(vp + 32 * 2048);  v3r = *(const uint4*)(vp + 48 * 2048); \
  } while (0)

  const float C_EXP2 = 0.18033688011112042f;  // 0.125 * log2(e)

  LOADT(t0);
  for (int t = t0; t < t1; ++t) {
    const int kv0 = t * 128;
    if (t > t0) __syncthreads();
    *(uint4*)&Ks[(size_t)sr * 72 + sc] = k0r;
    *(uint4*)&Ks[(size_t)(sr + 32) * 72 + sc] = k1r;
    *(uint4*)&Ks[(size_t)(sr + 64) * 72 + sc] = k2r;
    *(uint4*)&Ks[(size_t)(sr + 96) * 72 + sc] = k3r;
    *(uint4*)&Vt[(size_t)vr * 136 + vc] = v0r;
    *(uint4*)&Vt[(size_t)(vr + 16) * 136 + vc] = v1r;
    *(uint4*)&Vt[(size_t)(vr + 32) * 136 + vc] = v2r;
    *(uint4*)&Vt[(size_t)(vr + 48) * 136 + vc] = v3r;
    __syncthreads();

    if (t + 1 < t1) LOADT(t + 1);  // prefetch in flight across compute

    // S = Q K^T : [32 q] x [128 kv]; each K frag read feeds 2 MFMAs
    f32x4 s[2][8];
    #pragma unroll
    for (int g = 0; g < 2; g++)
      #pragma unroll
      for (int n = 0; n < 8; n++) s[g][n] = (f32x4){0.f, 0.f, 0.f, 0.f};
    __builtin_amdgcn_s_setprio(1);
    #pragma unroll
    for (int ks = 0; ks < 2; ks++)
      #pragma unroll
      for (int n = 0; n < 8; n++) {
        bf16x8 bk = *(bf16x8*)&Ks[(n * 16 + fr) * 72 + ks * 32 + fq * 8];
        s[0][n] = __builtin_amdgcn_mfma_f32_16x16x32_bf16(qf[0][ks], bk, s[0][n], 0, 0, 0);
        s[1][n] = __builtin_amdgcn_mfma_f32_16x16x32_bf16(qf[1][ks], bk, s[1][n], 0, 0, 0);
      }
    __builtin_amdgcn_s_setprio(0);

    // no-max softmax; packed P row store (kv-permuted: pos = 8*fr + n)
    const bool lastT = (t == k - 1);
    #pragma unroll
    for (int g = 0; g < 2; g++)
      #pragma unroll
      for (int j = 0; j < 4; j++) {
        const int qrow = qb0 + w * 32 + g * 16 + fq * 4 + j;
        float p[8];
        float rs = 0.f;
        #pragma unroll
        for (int n = 0; n < 8; n++) {
          float val = s[g][n][j] * C_EXP2;
          if (lastT && (kv0 + n * 16 + fr > qrow)) val = -1e30f;
          p[n] = __builtin_amdgcn_exp2f(val);
          rs += p[n];
        }
        l_[g][j] += rs;
        uint4 pk;
        pk.x = cvtpk(p[0], p[1]);
        pk.y = cvtpk(p[2], p[3]);
        pk.z = cvtpk(p[4], p[5]);
        pk.w = cvtpk(p[6], p[7]);
        *(uint4*)&P_[(g * 16 + fq * 4 + j) * 136 + 8 * fr] = pk;
      }

    // O += P V; each V frag read feeds 2 MFMAs
    __builtin_amdgcn_s_setprio(1);
    #pragma unroll
    for (int ks = 0; ks < 4; ks++) {
      bf16x8 pa0 = *(bf16x8*)&P_[fr * 136 + ks * 32 + fq * 8];
      bf16x8 pa1 = *(bf16x8*)&P_[(16 + fr) * 136 + ks * 32 + fq * 8];
      #pragma unroll
      for (int n2 = 0; n2 < 4; n2++) {
        bf16x8 vb8 = *(bf16x8*)&Vt[(n2 * 16 + fr) * 136 + ks * 32 + fq * 8];
        o[0][n2] = __builtin_amdgcn_mfma_f32_16x16x32_bf16(pa0, vb8, o[0][n2], 0, 0, 0);
        o[1][n2] = __builtin_amdgcn_mfma_f32_16x16x32_bf16(pa1, vb8, o[1][n2], 0, 0, 0);
      }
    }
    __builtin_amdgcn_s_setprio(0);
  }
#undef LOADT

  #pragma unroll
  for (int g = 0; g < 2; g++)
    #pragma unroll
    for (int j = 0; j < 4; j++) {
      float rs = l_[g][j];
      rs += __shfl_xor(rs, 1);
      rs += __shfl_xor(rs, 2);
      rs += __shfl_xor(rs, 4);
      rs += __shfl_xor(rs, 8);
      l_[g][j] = rs;
    }

  if (nch == 1) {
    #pragma unroll
    for (int g = 0; g < 2; g++)
      #pragma unroll
      for (int n2 = 0; n2 < 4; n2++)
        #pragma unroll
        for (int j = 0; j < 4; j++) {
          int qrow = qb0 + w * 32 + g * 16 + fq * 4 + j;
          y[((size_t)(b_ * 2048 + qrow)) * 1024 + h * 64 + n2 * 16 + fr] =
              f2bf(o[g][n2][j] / l_[g][j]);
        }
  } else {
    const size_t ob = ((size_t)i * 32 + bh) * 128 * 64;
    #pragma unroll
    for (int g = 0; g < 2; g++)
      #pragma unroll
      for (int n2 = 0; n2 < 4; n2++)
        #pragma unroll
        for (int j = 0; j < 4; j++) {
          int qr = w * 32 + g * 16 + fq * 4 + j;
          pO[ob + (size_t)qr * 64 + n2 * 16 + fr] = f2bf(o[g][n2][j]);
        }
    if (fr == 0) {
      #pragma unroll
      for (int g = 0; g < 2; g++)
        #pragma unroll
        for (int j = 0; j < 4; j++)
          pl[((size_t)i * 32 + bh) * 128 + w * 32 + g * 16 + fq * 4 + j] = l_[g][j];
    }
  }
}

// ---------------- combine partials (vectorized): y = (sum_c O_c) / (sum_c l_c) -------
// Only a>=4 rows (nch>=2). 49152 rows x 8 d-chunks = 1536 blocks x 256 thr.
// baseSlot closed form: a>=8 -> 71 - a*a/4 - a ; 4<=a<8 -> 52 + 2*(7-a).
__global__ __launch_bounds__(256) void attn_combine(const ushort* __restrict__ pO,
                                                    const float* __restrict__ pl,
                                                    ushort* __restrict__ y) {
  int flat = blockIdx.x * 256 + threadIdx.x;
  int d8 = (flat & 7) * 8;
  int ridx = flat >> 3;              // 0..49151
  int bh = ridx / 1536;
  int r = ridx - bh * 1536;
  int a = 4 + (r >> 7);
  int tloc = r & 127;
  int t = a * 128 + tloc;
  int nch = nch2_of(a);
  int baseSlot = (a >= 8) ? (71 - ((a * a) >> 2) - a) : (52 + 2 * (7 - a));
  float os0=0.f, os1=0.f, os2=0.f, os3=0.f, os4=0.f, os5=0.f, os6=0.f, os7=0.f;
  float ls = 0.f;
  for (int c = 0; c < nch; ++c) {
    int slot = baseSlot + c;
    uint4 v = *(const uint4*)&pO[((size_t)slot * 32 + bh) * 128 * 64 + (size_t)tloc * 64 + d8];
    os0 += bf2f((ushort)(v.x & 0xffff));  os1 += bf2f((ushort)(v.x >> 16));
    os2 += bf2f((ushort)(v.y & 0xffff));  os3 += bf2f((ushort)(v.y >> 16));
    os4 += bf2f((ushort)(v.z & 0xffff));  os5 += bf2f((ushort)(v.z >> 16));
    os6 += bf2f((ushort)(v.w & 0xffff));  os7 += bf2f((ushort)(v.w >> 16));
    ls += pl[((size_t)slot * 32 + bh) * 128 + tloc];
  }
  float inv = 1.f / ls;
  uint4 o;
  o.x = cvtpk(os0 * inv, os1 * inv);
  o.y = cvtpk(os2 * inv, os3 * inv);
  o.z = cvtpk(os4 * inv, os5 * inv);
  o.w = cvtpk(os6 * inv, os7 * inv);
  int b_ = bh >> 4, h = bh & 15;
  *(uint4*)&y[((size_t)(b_ * 2048 + t)) * 1024 + h * 64 + d8] = o;
}

extern "C" void kernel_launch(void* const* d_in, const int* in_sizes, int n_in,
                              void* d_out, int out_size, void* d_ws, size_t ws_size,
                              hipStream_t stream) {
  const float* x = (const float*)d_in[0];
  const float* wqkv = (const float*)d_in[1];
  const float* wproj = (const float*)d_in[2];
  float* out = (float*)d_out;

  ushort* ws = (ushort*)d_ws;
  ushort* xb = ws;                               // 4096*1024
  ushort* wqkvT = xb + 4096 * 1024;              // 3072*1024  [N][K]
  ushort* wprojT = wqkvT + 3072 * 1024;          // 1024*1024  [N][K]
  ushort* qb = wprojT + 1024 * 1024;             // [bh][t][64]
  ushort* kb = qb + 32 * 2048 * 64;              // [bh][t][64]
  ushort* vtb = kb + 32 * 2048 * 64;             // [bh][64][t'] kv-permuted
  ushort* yb = vtb + 32 * 2048 * 64;             // [B,T,1024]
  ushort* pO = yb + 4096 * 1024;                 // [64 slots][32][128][64] bf16
  float*  pl = (float*)(pO + (size_t)64 * 32 * 128 * 64);  // [64][32][128] f32

  prep<<<8192, 256, 0, stream>>>(x, wqkv, wproj, xb, wqkvT, wprojT);
  gemm_bf16<0, 128><<<768, 256, 0, stream>>>(xb, wqkvT, qb, kb, vtb, nullptr, 4096, 3072, 1024);
  attn_fwd<<<2048, 256, 0, stream>>>(qb, kb, vtb, yb, pO, pl);
  attn_combine<<<1536, 256, 0, stream>>>(pO, pl, yb);
  gemm_bf16<1, 64><<<512, 256, 0, stream>>>(yb, wprojT, nullptr, nullptr, nullptr, out, 4096, 1024, 1024);
}

// Round 19
// 115.215 us; speedup vs baseline: 1.3538x; 1.0211x over previous
//
#include <hip/hip_runtime.h>
#include <hip/hip_bf16.h>

// B=2, T=2048, D=1024, H=16, dh=64. f32 in/out, bf16 MFMA internally.
// R19 = R18 with causal-mask window fixed: with KVBLK=64 the diagonal spans
// the LAST TWO 64-tiles of each 128-row q-block (R18 masked only the last one
// -> absmax 3.38). maskT = (t >= k64-2). Everything else identical.

typedef __attribute__((ext_vector_type(8))) short bf16x8;
typedef __attribute__((ext_vector_type(4))) float f32x4;

__device__ __forceinline__ ushort f2bf(float f) {
  unsigned u = __builtin_bit_cast(unsigned, f);
  unsigned r = (u + 0x7fffu + ((u >> 16) & 1u)) >> 16;   // RNE
  return (ushort)r;
}
__device__ __forceinline__ float bf2f(ushort u) {
  unsigned v = ((unsigned)u) << 16;
  return __builtin_bit_cast(float, v);
}
__device__ __forceinline__ unsigned cvtpk(float a, float b) {  // [lo=a, hi=b] bf16, RNE
  unsigned r;
  asm("v_cvt_pk_bf16_f32 %0, %1, %2" : "=v"(r) : "v"(a), "v"(b));
  return r;
}

__device__ __forceinline__ void gload16(const ushort* g, ushort* l) {
  auto gp = (const __attribute__((address_space(1))) void*)g;
  auto lp = (__attribute__((address_space(3))) void*)l;
  __builtin_amdgcn_global_load_lds(gp, lp, 16, 0, 0);
}

// chunks per 128-row q-block a; must match attn/combine
__device__ __forceinline__ int nch2_of(int a) {
  if (a >= 8) return (a + 2) >> 1;
  if (a >= 4) return 2;
  return 1;
}

// ---------------- prep: x cvt + w_qkv^T + w_proj^T in ONE launch ----------------
__global__ __launch_bounds__(256) void prep(const float* __restrict__ x,
                                            const float* __restrict__ wq,
                                            const float* __restrict__ wp,
                                            ushort* __restrict__ xb,
                                            ushort* __restrict__ wqT,
                                            ushort* __restrict__ wpT) {
  __shared__ float tile[32][33];
  const int bx = blockIdx.x;
  if (bx < 4096) {
    int i = (bx * 256 + threadIdx.x) * 4;     // full |x| coverage
    float4 v = *(const float4*)(x + i);
    ushort4 o = { f2bf(v.x), f2bf(v.y), f2bf(v.z), f2bf(v.w) };
    *(ushort4*)(xb + i) = o;
    return;
  }
  const float* in;  ushort* out;  int C, b2;
  if (bx < 7168) { b2 = bx - 4096; in = wq; out = wqT; C = 3072; }
  else           { b2 = bx - 7168; in = wp; out = wpT; C = 1024; }
  const int R = 1024;
  int nbx = C / 32;
  int c0 = (b2 % nbx) * 32, r0 = (b2 / nbx) * 32;
  int tx = threadIdx.x & 31, ty = threadIdx.x >> 5;
  #pragma unroll
  for (int i = 0; i < 32; i += 8) tile[ty + i][tx] = in[(size_t)(r0 + ty + i) * C + c0 + tx];
  __syncthreads();
  if (threadIdx.x < 128) {
    int cr = threadIdx.x >> 2, m = threadIdx.x & 3;
    ushort vals[8];
    #pragma unroll
    for (int e = 0; e < 8; e++) vals[e] = f2bf(tile[8 * m + e][cr]);
    *(uint4*)&out[(size_t)(c0 + cr) * R + r0 + 8 * m] = *(uint4*)vals;
  }
}

// ---------------- bf16 GEMM: C[M,N] = A[M,K] * BT[N,K]^T, XCD-chunked 1D grid --------
template <int EPI, int BN>
__global__ __launch_bounds__(256) void gemm_bf16(const ushort* __restrict__ A,
                                                 const ushort* __restrict__ BT,
                                                 ushort* __restrict__ qo, ushort* __restrict__ ko,
                                                 ushort* __restrict__ vo, float* __restrict__ outf,
                                                 int M, int N, int K) {
  constexpr int NB = BN / 32;
  constexpr int ABU = 128 * 32 + BN * 32;
  constexpr int SHU = (EPI == 0 && 2 * 128 * 72 > ABU) ? 2 * 128 * 72 : ABU;
  __shared__ ushort sh[SHU];
  ushort* Als = sh;
  ushort* Bls = sh + 128 * 32;
  const int tid = threadIdx.x;
  const int lane = tid & 63;
  const int w = tid >> 6;
  const int wr = w >> 1, wc = w & 1;
  const int fr = lane & 15, fq = lane >> 4;
  const int flat = blockIdx.x;
  const int cpx = (32 * (N / BN)) >> 3;
  const int swz = (flat & 7) * cpx + (flat >> 3);
  const int bm0 = (swz & 31) * 128;
  const int bn0 = (swz >> 5) * BN;
  const int srow = lane >> 2;
  const int scol = (lane & 3) * 8;

  f32x4 acc[4][NB];
  #pragma unroll
  for (int m = 0; m < 4; m++)
    #pragma unroll
    for (int n = 0; n < NB; n++) acc[m][n] = (f32x4){0.f, 0.f, 0.f, 0.f};

  for (int k0 = 0; k0 < K; k0 += 32) {
    __syncthreads();
    #pragma unroll
    for (int c = 0; c < 2; c++) {
      int chunk = w * 2 + c;
      int rr = chunk * 16 + srow;
      gload16(&A[(size_t)(bm0 + rr) * K + k0 + scol], &Als[chunk * 512]);
    }
    #pragma unroll
    for (int c = 0; c < BN / 64; c++) {
      int chunk = w * (BN / 64) + c;
      int rr = chunk * 16 + srow;
      gload16(&BT[(size_t)(bn0 + rr) * K + k0 + scol], &Bls[chunk * 512]);
    }
    __syncthreads();
    bf16x8 a[4], b[NB];
    #pragma unroll
    for (int m = 0; m < 4; m++) a[m] = *(bf16x8*)&Als[(wr * 64 + m * 16 + fr) * 32 + fq * 8];
    #pragma unroll
    for (int n = 0; n < NB; n++) b[n] = *(bf16x8*)&Bls[(wc * (BN / 2) + n * 16 + fr) * 32 + fq * 8];
    __builtin_amdgcn_s_setprio(1);
    #pragma unroll
    for (int m = 0; m < 4; m++)
      #pragma unroll
      for (int n = 0; n < NB; n++)
        acc[m][n] = __builtin_amdgcn_mfma_f32_16x16x32_bf16(a[m], b[n], acc[m][n], 0, 0, 0);
    __builtin_amdgcn_s_setprio(0);
  }

  if (EPI == 0) {
    __syncthreads();
    ushort* vst = sh;
    #pragma unroll
    for (int m = 0; m < 4; m++)
      #pragma unroll
      for (int n = 0; n < NB; n++)
        #pragma unroll
        for (int jj = 0; jj < 4; jj++) {
          int lt = wr * 64 + m * 16 + fq * 4 + jj;
          int dd = n * 16 + fr;
          vst[(wc * 128 + lt) * 72 + dd] = f2bf(acc[m][n][jj]);
        }
    __syncthreads();
    const int b_ = bm0 >> 11, t0loc = bm0 & 2047;
    const int which = bn0 >> 10;
    const int hbase = (bn0 & 1023) >> 6;
    if (which < 2) {
      ushort* dst = (which == 0) ? qo : ko;
      #pragma unroll
      for (int p = 0; p < 8; p++) {
        int idx = tid + p * 256;
        int hh = idx >> 10, lt = (idx >> 3) & 127, c8 = (idx & 7) * 8;
        uint4 v = *(uint4*)&vst[(hh * 128 + lt) * 72 + c8];
        size_t bh = (size_t)(b_ * 16 + hbase + hh);
        *(uint4*)&dst[(bh * 2048 + t0loc + lt) * 64 + c8] = v;
      }
    } else {
      // V: transpose + 64-block kv-permute. pos p=8*m4+r <-> kv_local=16*(r&3)+2*m4+(r>>2)
      #pragma unroll
      for (int p = 0; p < 8; p++) {
        int idx = tid + p * 256;
        int hh = idx >> 10, d = (idx >> 4) & 63, m = idx & 15;
        int blk = m >> 3, m4 = m & 7;
        ushort vals[8];
        #pragma unroll
        for (int r = 0; r < 8; r++)
          vals[r] = vst[(hh * 128 + blk * 64 + 16 * (r & 3) + 2 * m4 + (r >> 2)) * 72 + d];
        size_t bh = (size_t)(b_ * 16 + hbase + hh);
        *(uint4*)&vo[(bh * 64 + d) * 2048 + t0loc + blk * 64 + 8 * m4] = *(uint4*)vals;
      }
    }
  } else {
    #pragma unroll
    for (int m = 0; m < 4; m++)
      #pragma unroll
      for (int n = 0; n < NB; n++)
        #pragma unroll
        for (int jj = 0; jj < 4; jj++) {
          int r = bm0 + wr * 64 + m * 16 + fq * 4 + jj;
          int c = bn0 + wc * (BN / 2) + n * 16 + fr;
          outf[(size_t)r * N + c] = acc[m][n][jj];
        }
  }
}

// ---------------- split-KV flash attention (causal), q32 waves, KVBLK=64 ----------
__global__ __launch_bounds__(256, 2) void attn_fwd(const ushort* __restrict__ qg,
                                                   const ushort* __restrict__ kg,
                                                   const ushort* __restrict__ vtg,
                                                   ushort* __restrict__ y,
                                                   ushort* __restrict__ pO,
                                                   float* __restrict__ pl) {
  __shared__ ushort Ks[64 * 72];       // [kv64][d64]
  __shared__ ushort Vt[64 * 72];       // [d64][kv'64] (64-block permuted)
  __shared__ ushort Ps[4][32 * 72];    // per-wave P [q32][kv'64]

  const int bh = blockIdx.x & 31;
  const int i = blockIdx.x >> 5;
  int acc = 0, a = 15, nch = 1;
  for (int q = 15; q >= 0; --q) {
    int nc = nch2_of(q);
    if (i < acc + nc) { a = q; nch = nc; break; }
    acc += nc;
  }
  const int ch = i - acc;
  const int k64 = 2 * (a + 1);                 // total 64-kv tiles
  const int ct = (a >= 8) ? 4 : 8;             // chunk size in 64-tiles
  const int t0 = ch * ct;
  const int t1 = (t0 + ct < k64) ? t0 + ct : k64;

  const int tid = threadIdx.x, lane = tid & 63, w = tid >> 6;
  const int fr = lane & 15, fq = lane >> 4;
  const size_t base = (size_t)bh * 2048 * 64;
  const int b_ = bh >> 4, h = bh & 15;
  const int qb0 = a * 128;
  ushort* P_ = Ps[w];

  const int kr = tid >> 2;
  const int kc8 = (tid & 3) * 8;
  const int vr = tid >> 3;
  const int vc8 = (tid & 7) * 8;
  const ushort* kg_l = kg + base + (size_t)kr * 64 + kc8;
  const ushort* vg_l = vtg + base + (size_t)vr * 2048 + vc8;

  bf16x8 qf[2][2];
  #pragma unroll
  for (int g = 0; g < 2; g++) {
    const ushort* qp = &qg[base + (size_t)(qb0 + w * 32 + g * 16 + fr) * 64];
    qf[g][0] = *(const bf16x8*)(qp + fq * 8);
    qf[g][1] = *(const bf16x8*)(qp + 32 + fq * 8);
  }

  f32x4 o[2][4];
  #pragma unroll
  for (int g = 0; g < 2; g++)
    #pragma unroll
    for (int n = 0; n < 4; n++) o[g][n] = (f32x4){0.f, 0.f, 0.f, 0.f};
  float l_[2][4] = {{0.f,0.f,0.f,0.f},{0.f,0.f,0.f,0.f}};

  uint4 k0r, k1r, v0r, v1r;  // named: cannot lower to scratch

#define LOADT(t)                                              \
  do {                                                        \
    const ushort* kp = kg_l + (size_t)(t) * 4096;             \
    k0r = *(const uint4*)(kp);                                \
    k1r = *(const uint4*)(kp + 32);                           \
    const ushort* vp = vg_l + (size_t)(t) * 64;               \
    v0r = *(const uint4*)(vp);                                \
    v1r = *(const uint4*)(vp + 32 * 2048);                    \
  } while (0)

  const float C_EXP2 = 0.18033688011112042f;  // 0.125 * log2(e)

  LOADT(t0);
  for (int t = t0; t < t1; ++t) {
    const int kv0 = t * 64;
    if (t > t0) __syncthreads();
    *(uint4*)&Ks[(size_t)kr * 72 + kc8] = k0r;
    *(uint4*)&Ks[(size_t)kr * 72 + kc8 + 32] = k1r;
    *(uint4*)&Vt[(size_t)vr * 72 + vc8] = v0r;
    *(uint4*)&Vt[(size_t)(vr + 32) * 72 + vc8] = v1r;
    __syncthreads();

    if (t + 1 < t1) LOADT(t + 1);  // prefetch in flight across compute

    // S = Q K^T : [32 q] x [64 kv]; each K frag read feeds 2 MFMAs
    f32x4 s[2][4];
    #pragma unroll
    for (int g = 0; g < 2; g++)
      #pragma unroll
      for (int n = 0; n < 4; n++) s[g][n] = (f32x4){0.f, 0.f, 0.f, 0.f};
    __builtin_amdgcn_s_setprio(1);
    #pragma unroll
    for (int ks = 0; ks < 2; ks++)
      #pragma unroll
      for (int n = 0; n < 4; n++) {
        bf16x8 bk = *(bf16x8*)&Ks[(n * 16 + fr) * 72 + ks * 32 + fq * 8];
        s[0][n] = __builtin_amdgcn_mfma_f32_16x16x32_bf16(qf[0][ks], bk, s[0][n], 0, 0, 0);
        s[1][n] = __builtin_amdgcn_mfma_f32_16x16x32_bf16(qf[1][ks], bk, s[1][n], 0, 0, 0);
      }
    __builtin_amdgcn_s_setprio(0);

    // no-max softmax; packed P row store (64-permuted: pos = 4*fr + n)
    // FIX: diagonal spans the last TWO 64-tiles of the q-block (mask both).
    const bool maskT = (t >= k64 - 2);
    #pragma unroll
    for (int g = 0; g < 2; g++)
      #pragma unroll
      for (int j = 0; j < 4; j++) {
        const int qrow = qb0 + w * 32 + g * 16 + fq * 4 + j;
        float p0, p1, p2, p3;
        {
          float v0 = s[g][0][j] * C_EXP2, v1 = s[g][1][j] * C_EXP2;
          float v2 = s[g][2][j] * C_EXP2, v3 = s[g][3][j] * C_EXP2;
          if (maskT) {
            if (kv0 +  0 + fr > qrow) v0 = -1e30f;
            if (kv0 + 16 + fr > qrow) v1 = -1e30f;
            if (kv0 + 32 + fr > qrow) v2 = -1e30f;
            if (kv0 + 48 + fr > qrow) v3 = -1e30f;
          }
          p0 = __builtin_amdgcn_exp2f(v0);
          p1 = __builtin_amdgcn_exp2f(v1);
          p2 = __builtin_amdgcn_exp2f(v2);
          p3 = __builtin_amdgcn_exp2f(v3);
        }
        l_[g][j] += (p0 + p1) + (p2 + p3);
        uint2 pk;
        pk.x = cvtpk(p0, p1);
        pk.y = cvtpk(p2, p3);
        *(uint2*)&P_[(g * 16 + fq * 4 + j) * 72 + 4 * fr] = pk;
      }

    // O += P V; each V frag read feeds 2 MFMAs
    __builtin_amdgcn_s_setprio(1);
    #pragma unroll
    for (int ks = 0; ks < 2; ks++) {
      bf16x8 pa0 = *(bf16x8*)&P_[fr * 72 + ks * 32 + fq * 8];
      bf16x8 pa1 = *(bf16x8*)&P_[(16 + fr) * 72 + ks * 32 + fq * 8];
      #pragma unroll
      for (int n2 = 0; n2 < 4; n2++) {
        bf16x8 vb8 = *(bf16x8*)&Vt[(n2 * 16 + fr) * 72 + ks * 32 + fq * 8];
        o[0][n2] = __builtin_amdgcn_mfma_f32_16x16x32_bf16(pa0, vb8, o[0][n2], 0, 0, 0);
        o[1][n2] = __builtin_amdgcn_mfma_f32_16x16x32_bf16(pa1, vb8, o[1][n2], 0, 0, 0);
      }
    }
    __builtin_amdgcn_s_setprio(0);
  }
#undef LOADT

  #pragma unroll
  for (int g = 0; g < 2; g++)
    #pragma unroll
    for (int j = 0; j < 4; j++) {
      float rs = l_[g][j];
      rs += __shfl_xor(rs, 1);
      rs += __shfl_xor(rs, 2);
      rs += __shfl_xor(rs, 4);
      rs += __shfl_xor(rs, 8);
      l_[g][j] = rs;
    }

  if (nch == 1) {
    #pragma unroll
    for (int g = 0; g < 2; g++)
      #pragma unroll
      for (int n2 = 0; n2 < 4; n2++)
        #pragma unroll
        for (int j = 0; j < 4; j++) {
          int qrow = qb0 + w * 32 + g * 16 + fq * 4 + j;
          y[((size_t)(b_ * 2048 + qrow)) * 1024 + h * 64 + n2 * 16 + fr] =
              f2bf(o[g][n2][j] / l_[g][j]);
        }
  } else {
    const size_t ob = ((size_t)i * 32 + bh) * 128 * 64;
    #pragma unroll
    for (int g = 0; g < 2; g++)
      #pragma unroll
      for (int n2 = 0; n2 < 4; n2++)
        #pragma unroll
        for (int j = 0; j < 4; j++) {
          int qr = w * 32 + g * 16 + fq * 4 + j;
          pO[ob + (size_t)qr * 64 + n2 * 16 + fr] = f2bf(o[g][n2][j]);
        }
    if (fr == 0) {
      #pragma unroll
      for (int g = 0; g < 2; g++)
        #pragma unroll
        for (int j = 0; j < 4; j++)
          pl[((size_t)i * 32 + bh) * 128 + w * 32 + g * 16 + fq * 4 + j] = l_[g][j];
    }
  }
}

// ---------------- combine partials (vectorized): y = (sum_c O_c) / (sum_c l_c) -------
__global__ __launch_bounds__(256) void attn_combine(const ushort* __restrict__ pO,
                                                    const float* __restrict__ pl,
                                                    ushort* __restrict__ y) {
  int flat = blockIdx.x * 256 + threadIdx.x;
  int d8 = (flat & 7) * 8;
  int ridx = flat >> 3;              // 0..49151
  int bh = ridx / 1536;
  int r = ridx - bh * 1536;
  int a = 4 + (r >> 7);
  int tloc = r & 127;
  int t = a * 128 + tloc;
  int nch = nch2_of(a);
  int baseSlot = (a >= 8) ? (71 - ((a * a) >> 2) - a) : (52 + 2 * (7 - a));
  float os0=0.f, os1=0.f, os2=0.f, os3=0.f, os4=0.f, os5=0.f, os6=0.f, os7=0.f;
  float ls = 0.f;
  for (int c = 0; c < nch; ++c) {
    int slot = baseSlot + c;
    uint4 v = *(const uint4*)&pO[((size_t)slot * 32 + bh) * 128 * 64 + (size_t)tloc * 64 + d8];
    os0 += bf2f((ushort)(v.x & 0xffff));  os1 += bf2f((ushort)(v.x >> 16));
    os2 += bf2f((ushort)(v.y & 0xffff));  os3 += bf2f((ushort)(v.y >> 16));
    os4 += bf2f((ushort)(v.z & 0xffff));  os5 += bf2f((ushort)(v.z >> 16));
    os6 += bf2f((ushort)(v.w & 0xffff));  os7 += bf2f((ushort)(v.w >> 16));
    ls += pl[((size_t)slot * 32 + bh) * 128 + tloc];
  }
  float inv = 1.f / ls;
  uint4 o;
  o.x = cvtpk(os0 * inv, os1 * inv);
  o.y = cvtpk(os2 * inv, os3 * inv);
  o.z = cvtpk(os4 * inv, os5 * inv);
  o.w = cvtpk(os6 * inv, os7 * inv);
  int b_ = bh >> 4, h = bh & 15;
  *(uint4*)&y[((size_t)(b_ * 2048 + t)) * 1024 + h * 64 + d8] = o;
}

extern "C" void kernel_launch(void* const* d_in, const int* in_sizes, int n_in,
                              void* d_out, int out_size, void* d_ws, size_t ws_size,
                              hipStream_t stream) {
  const float* x = (const float*)d_in[0];
  const float* wqkv = (const float*)d_in[1];
  const float* wproj = (const float*)d_in[2];
  float* out = (float*)d_out;

  ushort* ws = (ushort*)d_ws;
  ushort* xb = ws;                               // 4096*1024
  ushort* wqkvT = xb + 4096 * 1024;              // 3072*1024  [N][K]
  ushort* wprojT = wqkvT + 3072 * 1024;          // 1024*1024  [N][K]
  ushort* qb = wprojT + 1024 * 1024;             // [bh][t][64]
  ushort* kb = qb + 32 * 2048 * 64;              // [bh][t][64]
  ushort* vtb = kb + 32 * 2048 * 64;             // [bh][64][t'] 64-block kv-permuted
  ushort* yb = vtb + 32 * 2048 * 64;             // [B,T,1024]
  ushort* pO = yb + 4096 * 1024;                 // [64 slots][32][128][64] bf16
  float*  pl = (float*)(pO + (size_t)64 * 32 * 128 * 64);  // [64][32][128] f32

  prep<<<8192, 256, 0, stream>>>(x, wqkv, wproj, xb, wqkvT, wprojT);
  gemm_bf16<0, 128><<<768, 256, 0, stream>>>(xb, wqkvT, qb, kb, vtb, nullptr, 4096, 3072, 1024);
  attn_fwd<<<2048, 256, 0, stream>>>(qb, kb, vtb, yb, pO, pl);
  attn_combine<<<1536, 256, 0, stream>>>(pO, pl, yb);
  gemm_bf16<1, 64><<<512, 256, 0, stream>>>(yb, wprojT, nullptr, nullptr, nullptr, out, 4096, 1024, 1024);
}

// Round 20
// 108.878 us; speedup vs baseline: 1.4326x; 1.0582x over previous
//
#include <hip/hip_runtime.h>
#include <hip/hip_bf16.h>

// B=2, T=2048, D=1024, H=16, dh=64. f32 in/out, bf16 MFMA internally.
// R20: (a) GEMMs stage TWO BK=32 tiles per barrier pair (halves barrier-drain
// count; same conflict-free linear layout, LDS 32KB still under the 36.9KB
// epilogue buffer); (b) attn dispatches longest chunks first (slots 52-63
// mapped to the first blockIdx range; slot numbering unchanged).

typedef __attribute__((ext_vector_type(8))) short bf16x8;
typedef __attribute__((ext_vector_type(4))) float f32x4;

__device__ __forceinline__ ushort f2bf(float f) {
  unsigned u = __builtin_bit_cast(unsigned, f);
  unsigned r = (u + 0x7fffu + ((u >> 16) & 1u)) >> 16;   // RNE
  return (ushort)r;
}
__device__ __forceinline__ float bf2f(ushort u) {
  unsigned v = ((unsigned)u) << 16;
  return __builtin_bit_cast(float, v);
}
__device__ __forceinline__ unsigned cvtpk(float a, float b) {  // [lo=a, hi=b] bf16, RNE
  unsigned r;
  asm("v_cvt_pk_bf16_f32 %0, %1, %2" : "=v"(r) : "v"(a), "v"(b));
  return r;
}

__device__ __forceinline__ void gload16(const ushort* g, ushort* l) {
  auto gp = (const __attribute__((address_space(1))) void*)g;
  auto lp = (__attribute__((address_space(3))) void*)l;
  __builtin_amdgcn_global_load_lds(gp, lp, 16, 0, 0);
}

// chunks per 128-row q-block a; must match attn/combine
__device__ __forceinline__ int nch2_of(int a) {
  if (a >= 8) return (a + 2) >> 1;
  if (a >= 4) return 2;
  return 1;
}

// ---------------- prep: x cvt + w_qkv^T + w_proj^T in ONE launch ----------------
__global__ __launch_bounds__(256) void prep(const float* __restrict__ x,
                                            const float* __restrict__ wq,
                                            const float* __restrict__ wp,
                                            ushort* __restrict__ xb,
                                            ushort* __restrict__ wqT,
                                            ushort* __restrict__ wpT) {
  __shared__ float tile[32][33];
  const int bx = blockIdx.x;
  if (bx < 4096) {
    int i = (bx * 256 + threadIdx.x) * 4;     // full |x| coverage
    float4 v = *(const float4*)(x + i);
    ushort4 o = { f2bf(v.x), f2bf(v.y), f2bf(v.z), f2bf(v.w) };
    *(ushort4*)(xb + i) = o;
    return;
  }
  const float* in;  ushort* out;  int C, b2;
  if (bx < 7168) { b2 = bx - 4096; in = wq; out = wqT; C = 3072; }
  else           { b2 = bx - 7168; in = wp; out = wpT; C = 1024; }
  const int R = 1024;
  int nbx = C / 32;
  int c0 = (b2 % nbx) * 32, r0 = (b2 / nbx) * 32;
  int tx = threadIdx.x & 31, ty = threadIdx.x >> 5;
  #pragma unroll
  for (int i = 0; i < 32; i += 8) tile[ty + i][tx] = in[(size_t)(r0 + ty + i) * C + c0 + tx];
  __syncthreads();
  if (threadIdx.x < 128) {
    int cr = threadIdx.x >> 2, m = threadIdx.x & 3;
    ushort vals[8];
    #pragma unroll
    for (int e = 0; e < 8; e++) vals[e] = f2bf(tile[8 * m + e][cr]);
    *(uint4*)&out[(size_t)(c0 + cr) * R + r0 + 8 * m] = *(uint4*)vals;
  }
}

// ---------------- bf16 GEMM: C[M,N] = A[M,K] * BT[N,K]^T, XCD-chunked 1D grid --------
// Two BK=32 tiles staged per barrier pair (16 outer iters at K=1024).
template <int EPI, int BN>
__global__ __launch_bounds__(256) void gemm_bf16(const ushort* __restrict__ A,
                                                 const ushort* __restrict__ BT,
                                                 ushort* __restrict__ qo, ushort* __restrict__ ko,
                                                 ushort* __restrict__ vo, float* __restrict__ outf,
                                                 int M, int N, int K) {
  constexpr int NB = BN / 32;
  constexpr int ABU = 2 * 128 * 32 + 2 * BN * 32;          // dbuf A + dbuf B
  constexpr int SHU = (EPI == 0 && 2 * 128 * 72 > ABU) ? 2 * 128 * 72 : ABU;
  __shared__ ushort sh[SHU];
  ushort* AlsS[2] = { sh, sh + 4096 };
  ushort* BlsS[2] = { sh + 8192, sh + 8192 + BN * 32 };
  const int tid = threadIdx.x;
  const int lane = tid & 63;
  const int w = tid >> 6;
  const int wr = w >> 1, wc = w & 1;
  const int fr = lane & 15, fq = lane >> 4;
  const int flat = blockIdx.x;
  const int cpx = (32 * (N / BN)) >> 3;
  const int swz = (flat & 7) * cpx + (flat >> 3);
  const int bm0 = (swz & 31) * 128;
  const int bn0 = (swz >> 5) * BN;
  const int srow = lane >> 2;
  const int scol = (lane & 3) * 8;

  f32x4 acc[4][NB];
  #pragma unroll
  for (int m = 0; m < 4; m++)
    #pragma unroll
    for (int n = 0; n < NB; n++) acc[m][n] = (f32x4){0.f, 0.f, 0.f, 0.f};

  for (int k0 = 0; k0 < K; k0 += 64) {
    __syncthreads();
    #pragma unroll
    for (int s = 0; s < 2; s++) {
      int kk = k0 + s * 32;
      #pragma unroll
      for (int c = 0; c < 2; c++) {
        int chunk = w * 2 + c;
        int rr = chunk * 16 + srow;
        gload16(&A[(size_t)(bm0 + rr) * K + kk + scol], &AlsS[s][chunk * 512]);
      }
      #pragma unroll
      for (int c = 0; c < BN / 64; c++) {
        int chunk = w * (BN / 64) + c;
        int rr = chunk * 16 + srow;
        gload16(&BT[(size_t)(bn0 + rr) * K + kk + scol], &BlsS[s][chunk * 512]);
      }
    }
    __syncthreads();
    #pragma unroll
    for (int s = 0; s < 2; s++) {
      ushort* Als = AlsS[s];
      ushort* Bls = BlsS[s];
      bf16x8 a[4], b[NB];
      #pragma unroll
      for (int m = 0; m < 4; m++) a[m] = *(bf16x8*)&Als[(wr * 64 + m * 16 + fr) * 32 + fq * 8];
      #pragma unroll
      for (int n = 0; n < NB; n++) b[n] = *(bf16x8*)&Bls[(wc * (BN / 2) + n * 16 + fr) * 32 + fq * 8];
      __builtin_amdgcn_s_setprio(1);
      #pragma unroll
      for (int m = 0; m < 4; m++)
        #pragma unroll
        for (int n = 0; n < NB; n++)
          acc[m][n] = __builtin_amdgcn_mfma_f32_16x16x32_bf16(a[m], b[n], acc[m][n], 0, 0, 0);
      __builtin_amdgcn_s_setprio(0);
    }
  }

  if (EPI == 0) {
    __syncthreads();
    ushort* vst = sh;
    #pragma unroll
    for (int m = 0; m < 4; m++)
      #pragma unroll
      for (int n = 0; n < NB; n++)
        #pragma unroll
        for (int jj = 0; jj < 4; jj++) {
          int lt = wr * 64 + m * 16 + fq * 4 + jj;
          int dd = n * 16 + fr;
          vst[(wc * 128 + lt) * 72 + dd] = f2bf(acc[m][n][jj]);
        }
    __syncthreads();
    const int b_ = bm0 >> 11, t0loc = bm0 & 2047;
    const int which = bn0 >> 10;
    const int hbase = (bn0 & 1023) >> 6;
    if (which < 2) {
      ushort* dst = (which == 0) ? qo : ko;
      #pragma unroll
      for (int p = 0; p < 8; p++) {
        int idx = tid + p * 256;
        int hh = idx >> 10, lt = (idx >> 3) & 127, c8 = (idx & 7) * 8;
        uint4 v = *(uint4*)&vst[(hh * 128 + lt) * 72 + c8];
        size_t bh = (size_t)(b_ * 16 + hbase + hh);
        *(uint4*)&dst[(bh * 2048 + t0loc + lt) * 64 + c8] = v;
      }
    } else {
      // V: transpose + 64-block kv-permute. pos p=8*m4+r <-> kv_local=16*(r&3)+2*m4+(r>>2)
      #pragma unroll
      for (int p = 0; p < 8; p++) {
        int idx = tid + p * 256;
        int hh = idx >> 10, d = (idx >> 4) & 63, m = idx & 15;
        int blk = m >> 3, m4 = m & 7;
        ushort vals[8];
        #pragma unroll
        for (int r = 0; r < 8; r++)
          vals[r] = vst[(hh * 128 + blk * 64 + 16 * (r & 3) + 2 * m4 + (r >> 2)) * 72 + d];
        size_t bh = (size_t)(b_ * 16 + hbase + hh);
        *(uint4*)&vo[(bh * 64 + d) * 2048 + t0loc + blk * 64 + 8 * m4] = *(uint4*)vals;
      }
    }
  } else {
    #pragma unroll
    for (int m = 0; m < 4; m++)
      #pragma unroll
      for (int n = 0; n < NB; n++)
        #pragma unroll
        for (int jj = 0; jj < 4; jj++) {
          int r = bm0 + wr * 64 + m * 16 + fq * 4 + jj;
          int c = bn0 + wc * (BN / 2) + n * 16 + fr;
          outf[(size_t)r * N + c] = acc[m][n][jj];
        }
  }
}

// ---------------- split-KV flash attention (causal), q32 waves, KVBLK=64 ----------
// Longest chunks first: blockIdx r<12 -> slots 52..63 (8-tile chunks), else r-12.
__global__ __launch_bounds__(256, 2) void attn_fwd(const ushort* __restrict__ qg,
                                                   const ushort* __restrict__ kg,
                                                   const ushort* __restrict__ vtg,
                                                   ushort* __restrict__ y,
                                                   ushort* __restrict__ pO,
                                                   float* __restrict__ pl) {
  __shared__ ushort Ks[64 * 72];       // [kv64][d64]
  __shared__ ushort Vt[64 * 72];       // [d64][kv'64] (64-block permuted)
  __shared__ ushort Ps[4][32 * 72];    // per-wave P [q32][kv'64]

  const int bh = blockIdx.x & 31;
  const int r_ = blockIdx.x >> 5;
  const int i = (r_ < 12) ? (52 + r_) : (r_ - 12);   // dispatch-order permutation
  int acc = 0, a = 15, nch = 1;
  for (int q = 15; q >= 0; --q) {
    int nc = nch2_of(q);
    if (i < acc + nc) { a = q; nch = nc; break; }
    acc += nc;
  }
  const int ch = i - acc;
  const int k64 = 2 * (a + 1);                 // total 64-kv tiles
  const int ct = (a >= 8) ? 4 : 8;             // chunk size in 64-tiles
  const int t0 = ch * ct;
  const int t1 = (t0 + ct < k64) ? t0 + ct : k64;

  const int tid = threadIdx.x, lane = tid & 63, w = tid >> 6;
  const int fr = lane & 15, fq = lane >> 4;
  const size_t base = (size_t)bh * 2048 * 64;
  const int b_ = bh >> 4, h = bh & 15;
  const int qb0 = a * 128;
  ushort* P_ = Ps[w];

  const int kr = tid >> 2;
  const int kc8 = (tid & 3) * 8;
  const int vr = tid >> 3;
  const int vc8 = (tid & 7) * 8;
  const ushort* kg_l = kg + base + (size_t)kr * 64 + kc8;
  const ushort* vg_l = vtg + base + (size_t)vr * 2048 + vc8;

  bf16x8 qf[2][2];
  #pragma unroll
  for (int g = 0; g < 2; g++) {
    const ushort* qp = &qg[base + (size_t)(qb0 + w * 32 + g * 16 + fr) * 64];
    qf[g][0] = *(const bf16x8*)(qp + fq * 8);
    qf[g][1] = *(const bf16x8*)(qp + 32 + fq * 8);
  }

  f32x4 o[2][4];
  #pragma unroll
  for (int g = 0; g < 2; g++)
    #pragma unroll
    for (int n = 0; n < 4; n++) o[g][n] = (f32x4){0.f, 0.f, 0.f, 0.f};
  float l_[2][4] = {{0.f,0.f,0.f,0.f},{0.f,0.f,0.f,0.f}};

  uint4 k0r, k1r, v0r, v1r;  // named: cannot lower to scratch

#define LOADT(t)                                              \
  do {                                                        \
    const ushort* kp = kg_l + (size_t)(t) * 4096;             \
    k0r = *(const uint4*)(kp);                                \
    k1r = *(const uint4*)(kp + 32);                           \
    const ushort* vp = vg_l + (size_t)(t) * 64;               \
    v0r = *(const uint4*)(vp);                                \
    v1r = *(const uint4*)(vp + 32 * 2048);                    \
  } while (0)

  const float C_EXP2 = 0.18033688011112042f;  // 0.125 * log2(e)

  LOADT(t0);
  for (int t = t0; t < t1; ++t) {
    const int kv0 = t * 64;
    if (t > t0) __syncthreads();
    *(uint4*)&Ks[(size_t)kr * 72 + kc8] = k0r;
    *(uint4*)&Ks[(size_t)kr * 72 + kc8 + 32] = k1r;
    *(uint4*)&Vt[(size_t)vr * 72 + vc8] = v0r;
    *(uint4*)&Vt[(size_t)(vr + 32) * 72 + vc8] = v1r;
    __syncthreads();

    if (t + 1 < t1) LOADT(t + 1);  // prefetch in flight across compute

    // S = Q K^T : [32 q] x [64 kv]; each K frag read feeds 2 MFMAs
    f32x4 s[2][4];
    #pragma unroll
    for (int g = 0; g < 2; g++)
      #pragma unroll
      for (int n = 0; n < 4; n++) s[g][n] = (f32x4){0.f, 0.f, 0.f, 0.f};
    __builtin_amdgcn_s_setprio(1);
    #pragma unroll
    for (int ks = 0; ks < 2; ks++)
      #pragma unroll
      for (int n = 0; n < 4; n++) {
        bf16x8 bk = *(bf16x8*)&Ks[(n * 16 + fr) * 72 + ks * 32 + fq * 8];
        s[0][n] = __builtin_amdgcn_mfma_f32_16x16x32_bf16(qf[0][ks], bk, s[0][n], 0, 0, 0);
        s[1][n] = __builtin_amdgcn_mfma_f32_16x16x32_bf16(qf[1][ks], bk, s[1][n], 0, 0, 0);
      }
    __builtin_amdgcn_s_setprio(0);

    // no-max softmax; packed P row store (64-permuted: pos = 4*fr + n)
    // diagonal spans the last TWO 64-tiles of the q-block
    const bool maskT = (t >= k64 - 2);
    #pragma unroll
    for (int g = 0; g < 2; g++)
      #pragma unroll
      for (int j = 0; j < 4; j++) {
        const int qrow = qb0 + w * 32 + g * 16 + fq * 4 + j;
        float p0, p1, p2, p3;
        {
          float v0 = s[g][0][j] * C_EXP2, v1 = s[g][1][j] * C_EXP2;
          float v2 = s[g][2][j] * C_EXP2, v3 = s[g][3][j] * C_EXP2;
          if (maskT) {
            if (kv0 +  0 + fr > qrow) v0 = -1e30f;
            if (kv0 + 16 + fr > qrow) v1 = -1e30f;
            if (kv0 + 32 + fr > qrow) v2 = -1e30f;
            if (kv0 + 48 + fr > qrow) v3 = -1e30f;
          }
          p0 = __builtin_amdgcn_exp2f(v0);
          p1 = __builtin_amdgcn_exp2f(v1);
          p2 = __builtin_amdgcn_exp2f(v2);
          p3 = __builtin_amdgcn_exp2f(v3);
        }
        l_[g][j] += (p0 + p1) + (p2 + p3);
        uint2 pk;
        pk.x = cvtpk(p0, p1);
        pk.y = cvtpk(p2, p3);
        *(uint2*)&P_[(g * 16 + fq * 4 + j) * 72 + 4 * fr] = pk;
      }

    // O += P V; each V frag read feeds 2 MFMAs
    __builtin_amdgcn_s_setprio(1);
    #pragma unroll
    for (int ks = 0; ks < 2; ks++) {
      bf16x8 pa0 = *(bf16x8*)&P_[fr * 72 + ks * 32 + fq * 8];
      bf16x8 pa1 = *(bf16x8*)&P_[(16 + fr) * 72 + ks * 32 + fq * 8];
      #pragma unroll
      for (int n2 = 0; n2 < 4; n2++) {
        bf16x8 vb8 = *(bf16x8*)&Vt[(n2 * 16 + fr) * 72 + ks * 32 + fq * 8];
        o[0][n2] = __builtin_amdgcn_mfma_f32_16x16x32_bf16(pa0, vb8, o[0][n2], 0, 0, 0);
        o[1][n2] = __builtin_amdgcn_mfma_f32_16x16x32_bf16(pa1, vb8, o[1][n2], 0, 0, 0);
      }
    }
    __builtin_amdgcn_s_setprio(0);
  }
#undef LOADT

  #pragma unroll
  for (int g = 0; g < 2; g++)
    #pragma unroll
    for (int j = 0; j < 4; j++) {
      float rs = l_[g][j];
      rs += __shfl_xor(rs, 1);
      rs += __shfl_xor(rs, 2);
      rs += __shfl_xor(rs, 4);
      rs += __shfl_xor(rs, 8);
      l_[g][j] = rs;
    }

  if (nch == 1) {
    #pragma unroll
    for (int g = 0; g < 2; g++)
      #pragma unroll
      for (int n2 = 0; n2 < 4; n2++)
        #pragma unroll
        for (int j = 0; j < 4; j++) {
          int qrow = qb0 + w * 32 + g * 16 + fq * 4 + j;
          y[((size_t)(b_ * 2048 + qrow)) * 1024 + h * 64 + n2 * 16 + fr] =
              f2bf(o[g][n2][j] / l_[g][j]);
        }
  } else {
    const size_t ob = ((size_t)i * 32 + bh) * 128 * 64;
    #pragma unroll
    for (int g = 0; g < 2; g++)
      #pragma unroll
      for (int n2 = 0; n2 < 4; n2++)
        #pragma unroll
        for (int j = 0; j < 4; j++) {
          int qr = w * 32 + g * 16 + fq * 4 + j;
          pO[ob + (size_t)qr * 64 + n2 * 16 + fr] = f2bf(o[g][n2][j]);
        }
    if (fr == 0) {
      #pragma unroll
      for (int g = 0; g < 2; g++)
        #pragma unroll
        for (int j = 0; j < 4; j++)
          pl[((size_t)i * 32 + bh) * 128 + w * 32 + g * 16 + fq * 4 + j] = l_[g][j];
    }
  }
}

// ---------------- combine partials (vectorized): y = (sum_c O_c) / (sum_c l_c) -------
__global__ __launch_bounds__(256) void attn_combine(const ushort* __restrict__ pO,
                                                    const float* __restrict__ pl,
                                                    ushort* __restrict__ y) {
  int flat = blockIdx.x * 256 + threadIdx.x;
  int d8 = (flat & 7) * 8;
  int ridx = flat >> 3;              // 0..49151
  int bh = ridx / 1536;
  int r = ridx - bh * 1536;
  int a = 4 + (r >> 7);
  int tloc = r & 127;
  int t = a * 128 + tloc;
  int nch = nch2_of(a);
  int baseSlot = (a >= 8) ? (71 - ((a * a) >> 2) - a) : (52 + 2 * (7 - a));
  float os0=0.f, os1=0.f, os2=0.f, os3=0.f, os4=0.f, os5=0.f, os6=0.f, os7=0.f;
  float ls = 0.f;
  for (int c = 0; c < nch; ++c) {
    int slot = baseSlot + c;
    uint4 v = *(const uint4*)&pO[((size_t)slot * 32 + bh) * 128 * 64 + (size_t)tloc * 64 + d8];
    os0 += bf2f((ushort)(v.x & 0xffff));  os1 += bf2f((ushort)(v.x >> 16));
    os2 += bf2f((ushort)(v.y & 0xffff));  os3 += bf2f((ushort)(v.y >> 16));
    os4 += bf2f((ushort)(v.z & 0xffff));  os5 += bf2f((ushort)(v.z >> 16));
    os6 += bf2f((ushort)(v.w & 0xffff));  os7 += bf2f((ushort)(v.w >> 16));
    ls += pl[((size_t)slot * 32 + bh) * 128 + tloc];
  }
  float inv = 1.f / ls;
  uint4 o;
  o.x = cvtpk(os0 * inv, os1 * inv);
  o.y = cvtpk(os2 * inv, os3 * inv);
  o.z = cvtpk(os4 * inv, os5 * inv);
  o.w = cvtpk(os6 * inv, os7 * inv);
  int b_ = bh >> 4, h = bh & 15;
  *(uint4*)&y[((size_t)(b_ * 2048 + t)) * 1024 + h * 64 + d8] = o;
}

extern "C" void kernel_launch(void* const* d_in, const int* in_sizes, int n_in,
                              void* d_out, int out_size, void* d_ws, size_t ws_size,
                              hipStream_t stream) {
  const float* x = (const float*)d_in[0];
  const float* wqkv = (const float*)d_in[1];
  const float* wproj = (const float*)d_in[2];
  float* out = (float*)d_out;

  ushort* ws = (ushort*)d_ws;
  ushort* xb = ws;                               // 4096*1024
  ushort* wqkvT = xb + 4096 * 1024;              // 3072*1024  [N][K]
  ushort* wprojT = wqkvT + 3072 * 1024;          // 1024*1024  [N][K]
  ushort* qb = wprojT + 1024 * 1024;             // [bh][t][64]
  ushort* kb = qb + 32 * 2048 * 64;              // [bh][t][64]
  ushort* vtb = kb + 32 * 2048 * 64;             // [bh][64][t'] 64-block kv-permuted
  ushort* yb = vtb + 32 * 2048 * 64;             // [B,T,1024]
  ushort* pO = yb + 4096 * 1024;                 // [64 slots][32][128][64] bf16
  float*  pl = (float*)(pO + (size_t)64 * 32 * 128 * 64);  // [64][32][128] f32

  prep<<<8192, 256, 0, stream>>>(x, wqkv, wproj, xb, wqkvT, wprojT);
  gemm_bf16<0, 128><<<768, 256, 0, stream>>>(xb, wqkvT, qb, kb, vtb, nullptr, 4096, 3072, 1024);
  attn_fwd<<<2048, 256, 0, stream>>>(qb, kb, vtb, yb, pO, pl);
  attn_combine<<<1536, 256, 0, stream>>>(pO, pl, yb);
  gemm_bf16<1, 64><<<512, 256, 0, stream>>>(yb, wprojT, nullptr, nullptr, nullptr, out, 4096, 1024, 1024);
}

// Round 23
// 106.928 us; speedup vs baseline: 1.4587x; 1.0182x over previous
//
#include <hip/hip_runtime.h>
#include <hip/hip_bf16.h>

// B=2, T=2048, D=1024, H=16, dh=64. f32 in/out, bf16 MFMA internally.
// R23 = R20 (last good, 108.9us) + ONLY Q-pre-scale by 0.125*log2(e) in gemm0
// epilogue (exp2-domain softmax, no per-element scale mul in attn).
// Bisect: R22 proved ones-MFMA l-sum is the broken half of R21 -> closed.
// l-path stays R20's VALU accumulate + shuffle reduce (proven).

typedef __attribute__((ext_vector_type(8))) short bf16x8;
typedef __attribute__((ext_vector_type(4))) float f32x4;

__device__ __forceinline__ ushort f2bf(float f) {
  unsigned u = __builtin_bit_cast(unsigned, f);
  unsigned r = (u + 0x7fffu + ((u >> 16) & 1u)) >> 16;   // RNE
  return (ushort)r;
}
__device__ __forceinline__ float bf2f(ushort u) {
  unsigned v = ((unsigned)u) << 16;
  return __builtin_bit_cast(float, v);
}
__device__ __forceinline__ unsigned cvtpk(float a, float b) {  // [lo=a, hi=b] bf16, RNE
  unsigned r;
  asm("v_cvt_pk_bf16_f32 %0, %1, %2" : "=v"(r) : "v"(a), "v"(b));
  return r;
}

__device__ __forceinline__ void gload16(const ushort* g, ushort* l) {
  auto gp = (const __attribute__((address_space(1))) void*)g;
  auto lp = (__attribute__((address_space(3))) void*)l;
  __builtin_amdgcn_global_load_lds(gp, lp, 16, 0, 0);
}

// chunks per 128-row q-block a; must match attn/combine
__device__ __forceinline__ int nch2_of(int a) {
  if (a >= 8) return (a + 2) >> 1;
  if (a >= 4) return 2;
  return 1;
}

// ---------------- prep: x cvt + w_qkv^T + w_proj^T in ONE launch ----------------
__global__ __launch_bounds__(256) void prep(const float* __restrict__ x,
                                            const float* __restrict__ wq,
                                            const float* __restrict__ wp,
                                            ushort* __restrict__ xb,
                                            ushort* __restrict__ wqT,
                                            ushort* __restrict__ wpT) {
  __shared__ float tile[32][33];
  const int bx = blockIdx.x;
  if (bx < 4096) {
    int i = (bx * 256 + threadIdx.x) * 4;     // full |x| coverage
    float4 v = *(const float4*)(x + i);
    ushort4 o = { f2bf(v.x), f2bf(v.y), f2bf(v.z), f2bf(v.w) };
    *(ushort4*)(xb + i) = o;
    return;
  }
  const float* in;  ushort* out;  int C, b2;
  if (bx < 7168) { b2 = bx - 4096; in = wq; out = wqT; C = 3072; }
  else           { b2 = bx - 7168; in = wp; out = wpT; C = 1024; }
  const int R = 1024;
  int nbx = C / 32;
  int c0 = (b2 % nbx) * 32, r0 = (b2 / nbx) * 32;
  int tx = threadIdx.x & 31, ty = threadIdx.x >> 5;
  #pragma unroll
  for (int i = 0; i < 32; i += 8) tile[ty + i][tx] = in[(size_t)(r0 + ty + i) * C + c0 + tx];
  __syncthreads();
  if (threadIdx.x < 128) {
    int cr = threadIdx.x >> 2, m = threadIdx.x & 3;
    ushort vals[8];
    #pragma unroll
    for (int e = 0; e < 8; e++) vals[e] = f2bf(tile[8 * m + e][cr]);
    *(uint4*)&out[(size_t)(c0 + cr) * R + r0 + 8 * m] = *(uint4*)vals;
  }
}

// ---------------- bf16 GEMM: C[M,N] = A[M,K] * BT[N,K]^T, XCD-chunked 1D grid --------
// Two BK=32 tiles staged per barrier pair. EPI=0: q output pre-scaled by
// 0.125*log2(e); V transposed + 64-block kv-permuted.
template <int EPI, int BN>
__global__ __launch_bounds__(256) void gemm_bf16(const ushort* __restrict__ A,
                                                 const ushort* __restrict__ BT,
                                                 ushort* __restrict__ qo, ushort* __restrict__ ko,
                                                 ushort* __restrict__ vo, float* __restrict__ outf,
                                                 int M, int N, int K) {
  constexpr int NB = BN / 32;
  constexpr int ABU = 2 * 128 * 32 + 2 * BN * 32;          // dbuf A + dbuf B
  constexpr int SHU = (EPI == 0 && 2 * 128 * 72 > ABU) ? 2 * 128 * 72 : ABU;
  __shared__ ushort sh[SHU];
  ushort* AlsS[2] = { sh, sh + 4096 };
  ushort* BlsS[2] = { sh + 8192, sh + 8192 + BN * 32 };
  const int tid = threadIdx.x;
  const int lane = tid & 63;
  const int w = tid >> 6;
  const int wr = w >> 1, wc = w & 1;
  const int fr = lane & 15, fq = lane >> 4;
  const int flat = blockIdx.x;
  const int cpx = (32 * (N / BN)) >> 3;
  const int swz = (flat & 7) * cpx + (flat >> 3);
  const int bm0 = (swz & 31) * 128;
  const int bn0 = (swz >> 5) * BN;
  const int srow = lane >> 2;
  const int scol = (lane & 3) * 8;

  f32x4 acc[4][NB];
  #pragma unroll
  for (int m = 0; m < 4; m++)
    #pragma unroll
    for (int n = 0; n < NB; n++) acc[m][n] = (f32x4){0.f, 0.f, 0.f, 0.f};

  for (int k0 = 0; k0 < K; k0 += 64) {
    __syncthreads();
    #pragma unroll
    for (int s = 0; s < 2; s++) {
      int kk = k0 + s * 32;
      #pragma unroll
      for (int c = 0; c < 2; c++) {
        int chunk = w * 2 + c;
        int rr = chunk * 16 + srow;
        gload16(&A[(size_t)(bm0 + rr) * K + kk + scol], &AlsS[s][chunk * 512]);
      }
      #pragma unroll
      for (int c = 0; c < BN / 64; c++) {
        int chunk = w * (BN / 64) + c;
        int rr = chunk * 16 + srow;
        gload16(&BT[(size_t)(bn0 + rr) * K + kk + scol], &BlsS[s][chunk * 512]);
      }
    }
    __syncthreads();
    #pragma unroll
    for (int s = 0; s < 2; s++) {
      ushort* Als = AlsS[s];
      ushort* Bls = BlsS[s];
      bf16x8 a[4], b[NB];
      #pragma unroll
      for (int m = 0; m < 4; m++) a[m] = *(bf16x8*)&Als[(wr * 64 + m * 16 + fr) * 32 + fq * 8];
      #pragma unroll
      for (int n = 0; n < NB; n++) b[n] = *(bf16x8*)&Bls[(wc * (BN / 2) + n * 16 + fr) * 32 + fq * 8];
      __builtin_amdgcn_s_setprio(1);
      #pragma unroll
      for (int m = 0; m < 4; m++)
        #pragma unroll
        for (int n = 0; n < NB; n++)
          acc[m][n] = __builtin_amdgcn_mfma_f32_16x16x32_bf16(a[m], b[n], acc[m][n], 0, 0, 0);
      __builtin_amdgcn_s_setprio(0);
    }
  }

  if (EPI == 0) {
    const int which = bn0 >> 10;
    const float qscl = (which == 0) ? 0.18033688011112042f : 1.0f;  // 0.125*log2(e)
    __syncthreads();
    ushort* vst = sh;
    #pragma unroll
    for (int m = 0; m < 4; m++)
      #pragma unroll
      for (int n = 0; n < NB; n++)
        #pragma unroll
        for (int jj = 0; jj < 4; jj++) {
          int lt = wr * 64 + m * 16 + fq * 4 + jj;
          int dd = n * 16 + fr;
          vst[(wc * 128 + lt) * 72 + dd] = f2bf(acc[m][n][jj] * qscl);
        }
    __syncthreads();
    const int b_ = bm0 >> 11, t0loc = bm0 & 2047;
    const int hbase = (bn0 & 1023) >> 6;
    if (which < 2) {
      ushort* dst = (which == 0) ? qo : ko;
      #pragma unroll
      for (int p = 0; p < 8; p++) {
        int idx = tid + p * 256;
        int hh = idx >> 10, lt = (idx >> 3) & 127, c8 = (idx & 7) * 8;
        uint4 v = *(uint4*)&vst[(hh * 128 + lt) * 72 + c8];
        size_t bh = (size_t)(b_ * 16 + hbase + hh);
        *(uint4*)&dst[(bh * 2048 + t0loc + lt) * 64 + c8] = v;
      }
    } else {
      // V: transpose + 64-block kv-permute. pos p=8*m4+r <-> kv_local=16*(r&3)+2*m4+(r>>2)
      #pragma unroll
      for (int p = 0; p < 8; p++) {
        int idx = tid + p * 256;
        int hh = idx >> 10, d = (idx >> 4) & 63, m = idx & 15;
        int blk = m >> 3, m4 = m & 7;
        ushort vals[8];
        #pragma unroll
        for (int r = 0; r < 8; r++)
          vals[r] = vst[(hh * 128 + blk * 64 + 16 * (r & 3) + 2 * m4 + (r >> 2)) * 72 + d];
        size_t bh = (size_t)(b_ * 16 + hbase + hh);
        *(uint4*)&vo[(bh * 64 + d) * 2048 + t0loc + blk * 64 + 8 * m4] = *(uint4*)vals;
      }
    }
  } else {
    #pragma unroll
    for (int m = 0; m < 4; m++)
      #pragma unroll
      for (int n = 0; n < NB; n++)
        #pragma unroll
        for (int jj = 0; jj < 4; jj++) {
          int r = bm0 + wr * 64 + m * 16 + fq * 4 + jj;
          int c = bn0 + wc * (BN / 2) + n * 16 + fr;
          outf[(size_t)r * N + c] = acc[m][n][jj];
        }
  }
}

// ---------------- split-KV flash attention (causal), q32 waves, KVBLK=64 ----------
// Q pre-scaled (exp2 domain). l-path = R20's VALU accumulate + shuffle reduce.
// Longest chunks dispatched first.
__global__ __launch_bounds__(256, 2) void attn_fwd(const ushort* __restrict__ qg,
                                                   const ushort* __restrict__ kg,
                                                   const ushort* __restrict__ vtg,
                                                   ushort* __restrict__ y,
                                                   ushort* __restrict__ pO,
                                                   float* __restrict__ pl) {
  __shared__ ushort Ks[64 * 72];       // [kv64][d64]
  __shared__ ushort Vt[64 * 72];       // [d64][kv'64] (64-block permuted)
  __shared__ ushort Ps[4][32 * 72];    // per-wave P [q32][kv'64]

  const int bh = blockIdx.x & 31;
  const int r_ = blockIdx.x >> 5;
  const int i = (r_ < 12) ? (52 + r_) : (r_ - 12);   // dispatch-order permutation
  int acc = 0, a = 15, nch = 1;
  for (int q = 15; q >= 0; --q) {
    int nc = nch2_of(q);
    if (i < acc + nc) { a = q; nch = nc; break; }
    acc += nc;
  }
  const int ch = i - acc;
  const int k64 = 2 * (a + 1);                 // total 64-kv tiles
  const int ct = (a >= 8) ? 4 : 8;             // chunk size in 64-tiles
  const int t0 = ch * ct;
  const int t1 = (t0 + ct < k64) ? t0 + ct : k64;

  const int tid = threadIdx.x, lane = tid & 63, w = tid >> 6;
  const int fr = lane & 15, fq = lane >> 4;
  const size_t base = (size_t)bh * 2048 * 64;
  const int b_ = bh >> 4, h = bh & 15;
  const int qb0 = a * 128;
  ushort* P_ = Ps[w];

  const int kr = tid >> 2;
  const int kc8 = (tid & 3) * 8;
  const int vr = tid >> 3;
  const int vc8 = (tid & 7) * 8;
  const ushort* kg_l = kg + base + (size_t)kr * 64 + kc8;
  const ushort* vg_l = vtg + base + (size_t)vr * 2048 + vc8;

  bf16x8 qf[2][2];
  #pragma unroll
  for (int g = 0; g < 2; g++) {
    const ushort* qp = &qg[base + (size_t)(qb0 + w * 32 + g * 16 + fr) * 64];
    qf[g][0] = *(const bf16x8*)(qp + fq * 8);
    qf[g][1] = *(const bf16x8*)(qp + 32 + fq * 8);
  }

  f32x4 o[2][4];
  #pragma unroll
  for (int g = 0; g < 2; g++)
    #pragma unroll
    for (int n = 0; n < 4; n++) o[g][n] = (f32x4){0.f, 0.f, 0.f, 0.f};
  float l_[2][4] = {{0.f,0.f,0.f,0.f},{0.f,0.f,0.f,0.f}};

  uint4 k0r, k1r, v0r, v1r;  // named: cannot lower to scratch

#define LOADT(t)                                              \
  do {                                                        \
    const ushort* kp = kg_l + (size_t)(t) * 4096;             \
    k0r = *(const uint4*)(kp);                                \
    k1r = *(const uint4*)(kp + 32);                           \
    const ushort* vp = vg_l + (size_t)(t) * 64;               \
    v0r = *(const uint4*)(vp);                                \
    v1r = *(const uint4*)(vp + 32 * 2048);                    \
  } while (0)

  LOADT(t0);
  for (int t = t0; t < t1; ++t) {
    const int kv0 = t * 64;
    if (t > t0) __syncthreads();
    *(uint4*)&Ks[(size_t)kr * 72 + kc8] = k0r;
    *(uint4*)&Ks[(size_t)kr * 72 + kc8 + 32] = k1r;
    *(uint4*)&Vt[(size_t)vr * 72 + vc8] = v0r;
    *(uint4*)&Vt[(size_t)(vr + 32) * 72 + vc8] = v1r;
    __syncthreads();

    if (t + 1 < t1) LOADT(t + 1);  // prefetch in flight across compute

    // S = Q K^T : [32 q] x [64 kv]; Q pre-scaled so S is already exp2-domain
    f32x4 s[2][4];
    #pragma unroll
    for (int g = 0; g < 2; g++)
      #pragma unroll
      for (int n = 0; n < 4; n++) s[g][n] = (f32x4){0.f, 0.f, 0.f, 0.f};
    __builtin_amdgcn_s_setprio(1);
    #pragma unroll
    for (int ks = 0; ks < 2; ks++)
      #pragma unroll
      for (int n = 0; n < 4; n++) {
        bf16x8 bk = *(bf16x8*)&Ks[(n * 16 + fr) * 72 + ks * 32 + fq * 8];
        s[0][n] = __builtin_amdgcn_mfma_f32_16x16x32_bf16(qf[0][ks], bk, s[0][n], 0, 0, 0);
        s[1][n] = __builtin_amdgcn_mfma_f32_16x16x32_bf16(qf[1][ks], bk, s[1][n], 0, 0, 0);
      }
    __builtin_amdgcn_s_setprio(0);

    // no-max softmax (exp2 domain, no scale mul); packed P row store (pos = 4*fr + n)
    // diagonal spans the last TWO 64-tiles of the q-block
    const bool maskT = (t >= k64 - 2);
    #pragma unroll
    for (int g = 0; g < 2; g++)
      #pragma unroll
      for (int j = 0; j < 4; j++) {
        const int qrow = qb0 + w * 32 + g * 16 + fq * 4 + j;
        float v0 = s[g][0][j], v1 = s[g][1][j], v2 = s[g][2][j], v3 = s[g][3][j];
        if (maskT) {
          if (kv0 +  0 + fr > qrow) v0 = -1e30f;
          if (kv0 + 16 + fr > qrow) v1 = -1e30f;
          if (kv0 + 32 + fr > qrow) v2 = -1e30f;
          if (kv0 + 48 + fr > qrow) v3 = -1e30f;
        }
        float p0 = __builtin_amdgcn_exp2f(v0), p1 = __builtin_amdgcn_exp2f(v1);
        float p2 = __builtin_amdgcn_exp2f(v2), p3 = __builtin_amdgcn_exp2f(v3);
        l_[g][j] += (p0 + p1) + (p2 + p3);
        uint2 pk;
        pk.x = cvtpk(p0, p1);
        pk.y = cvtpk(p2, p3);
        *(uint2*)&P_[(g * 16 + fq * 4 + j) * 72 + 4 * fr] = pk;
      }

    // O += P V; each V frag read feeds 2 MFMAs
    __builtin_amdgcn_s_setprio(1);
    #pragma unroll
    for (int ks = 0; ks < 2; ks++) {
      bf16x8 pa0 = *(bf16x8*)&P_[fr * 72 + ks * 32 + fq * 8];
      bf16x8 pa1 = *(bf16x8*)&P_[(16 + fr) * 72 + ks * 32 + fq * 8];
      #pragma unroll
      for (int n2 = 0; n2 < 4; n2++) {
        bf16x8 vb8 = *(bf16x8*)&Vt[(n2 * 16 + fr) * 72 + ks * 32 + fq * 8];
        o[0][n2] = __builtin_amdgcn_mfma_f32_16x16x32_bf16(pa0, vb8, o[0][n2], 0, 0, 0);
        o[1][n2] = __builtin_amdgcn_mfma_f32_16x16x32_bf16(pa1, vb8, o[1][n2], 0, 0, 0);
      }
    }
    __builtin_amdgcn_s_setprio(0);
  }
#undef LOADT

  #pragma unroll
  for (int g = 0; g < 2; g++)
    #pragma unroll
    for (int j = 0; j < 4; j++) {
      float rs = l_[g][j];
      rs += __shfl_xor(rs, 1);
      rs += __shfl_xor(rs, 2);
      rs += __shfl_xor(rs, 4);
      rs += __shfl_xor(rs, 8);
      l_[g][j] = rs;
    }

  if (nch == 1) {
    #pragma unroll
    for (int g = 0; g < 2; g++)
      #pragma unroll
      for (int n2 = 0; n2 < 4; n2++)
        #pragma unroll
        for (int j = 0; j < 4; j++) {
          int qrow = qb0 + w * 32 + g * 16 + fq * 4 + j;
          y[((size_t)(b_ * 2048 + qrow)) * 1024 + h * 64 + n2 * 16 + fr] =
              f2bf(o[g][n2][j] / l_[g][j]);
        }
  } else {
    const size_t ob = ((size_t)i * 32 + bh) * 128 * 64;
    #pragma unroll
    for (int g = 0; g < 2; g++)
      #pragma unroll
      for (int n2 = 0; n2 < 4; n2++)
        #pragma unroll
        for (int j = 0; j < 4; j++) {
          int qr = w * 32 + g * 16 + fq * 4 + j;
          pO[ob + (size_t)qr * 64 + n2 * 16 + fr] = f2bf(o[g][n2][j]);
        }
    if (fr == 0) {
      #pragma unroll
      for (int g = 0; g < 2; g++)
        #pragma unroll
        for (int j = 0; j < 4; j++)
          pl[((size_t)i * 32 + bh) * 128 + w * 32 + g * 16 + fq * 4 + j] = l_[g][j];
    }
  }
}

// ---------------- combine partials (vectorized): y = (sum_c O_c) / (sum_c l_c) -------
__global__ __launch_bounds__(256) void attn_combine(const ushort* __restrict__ pO,
                                                    const float* __restrict__ pl,
                                                    ushort* __restrict__ y) {
  int flat = blockIdx.x * 256 + threadIdx.x;
  int d8 = (flat & 7) * 8;
  int ridx = flat >> 3;              // 0..49151
  int bh = ridx / 1536;
  int r = ridx - bh * 1536;
  int a = 4 + (r >> 7);
  int tloc = r & 127;
  int t = a * 128 + tloc;
  int nch = nch2_of(a);
  int baseSlot = (a >= 8) ? (71 - ((a * a) >> 2) - a) : (52 + 2 * (7 - a));
  float os0=0.f, os1=0.f, os2=0.f, os3=0.f, os4=0.f, os5=0.f, os6=0.f, os7=0.f;
  float ls = 0.f;
  for (int c = 0; c < nch; ++c) {
    int slot = baseSlot + c;
    uint4 v = *(const uint4*)&pO[((size_t)slot * 32 + bh) * 128 * 64 + (size_t)tloc * 64 + d8];
    os0 += bf2f((ushort)(v.x & 0xffff));  os1 += bf2f((ushort)(v.x >> 16));
    os2 += bf2f((ushort)(v.y & 0xffff));  os3 += bf2f((ushort)(v.y >> 16));
    os4 += bf2f((ushort)(v.z & 0xffff));  os5 += bf2f((ushort)(v.z >> 16));
    os6 += bf2f((ushort)(v.w & 0xffff));  os7 += bf2f((ushort)(v.w >> 16));
    ls += pl[((size_t)slot * 32 + bh) * 128 + tloc];
  }
  float inv = 1.f / ls;
  uint4 o;
  o.x = cvtpk(os0 * inv, os1 * inv);
  o.y = cvtpk(os2 * inv, os3 * inv);
  o.z = cvtpk(os4 * inv, os5 * inv);
  o.w = cvtpk(os6 * inv, os7 * inv);
  int b_ = bh >> 4, h = bh & 15;
  *(uint4*)&y[((size_t)(b_ * 2048 + t)) * 1024 + h * 64 + d8] = o;
}

extern "C" void kernel_launch(void* const* d_in, const int* in_sizes, int n_in,
                              void* d_out, int out_size, void* d_ws, size_t ws_size,
                              hipStream_t stream) {
  const float* x = (const float*)d_in[0];
  const float* wqkv = (const float*)d_in[1];
  const float* wproj = (const float*)d_in[2];
  float* out = (float*)d_out;

  ushort* ws = (ushort*)d_ws;
  ushort* xb = ws;                               // 4096*1024
  ushort* wqkvT = xb + 4096 * 1024;              // 3072*1024  [N][K]
  ushort* wprojT = wqkvT + 3072 * 1024;          // 1024*1024  [N][K]
  ushort* qb = wprojT + 1024 * 1024;             // [bh][t][64] (pre-scaled)
  ushort* kb = qb + 32 * 2048 * 64;              // [bh][t][64]
  ushort* vtb = kb + 32 * 2048 * 64;             // [bh][64][t'] 64-block kv-permuted
  ushort* yb = vtb + 32 * 2048 * 64;             // [B,T,1024]
  ushort* pO = yb + 4096 * 1024;                 // [64 slots][32][128][64] bf16
  float*  pl = (float*)(pO + (size_t)64 * 32 * 128 * 64);  // [64][32][128] f32

  prep<<<8192, 256, 0, stream>>>(x, wqkv, wproj, xb, wqkvT, wprojT);
  gemm_bf16<0, 128><<<768, 256, 0, stream>>>(xb, wqkvT, qb, kb, vtb, nullptr, 4096, 3072, 1024);
  attn_fwd<<<2048, 256, 0, stream>>>(qb, kb, vtb, yb, pO, pl);
  attn_combine<<<1536, 256, 0, stream>>>(pO, pl, yb);
  gemm_bf16<1, 64><<<512, 256, 0, stream>>>(yb, wprojT, nullptr, nullptr, nullptr, out, 4096, 1024, 1024);
}